// Round 9
// baseline (2388.716 us; speedup 1.0000x reference)
//
#include <hip/hip_runtime.h>
#include <math.h>

typedef unsigned short u16;
typedef unsigned int u32;

#define N_NODES 20000
#define MP      20480            // N padded to multiple of 1024 (128 x 8 XCD groups)
#define T_SEQ   8
#define DS      16
#define DD      8
#define E_EDGES 320000
#define HL      128
#define GH      4
#define GC      128
#define HC      512
#define EMB     64
#define KP1     160              // padded K for LSTM (136) and GAT1 (144)
#define EP      (E_EDGES + N_NODES)

typedef __attribute__((ext_vector_type(8))) short bf16x8;
typedef __attribute__((ext_vector_type(4))) float f32x4;

__device__ __forceinline__ u16 f2bf(float f) {
  u32 u = __float_as_uint(f);
  u += 0x7fff + ((u >> 16) & 1);   // RNE (inputs are finite)
  return (u16)(u >> 16);
}
__device__ __forceinline__ float bflo(u32 v) { return __uint_as_float(v << 16); }
__device__ __forceinline__ float bfhi(u32 v) { return __uint_as_float(v & 0xffff0000u); }
__device__ __forceinline__ float bf16f(u16 v) { return __uint_as_float((u32)v << 16); }

__device__ __forceinline__ void gld16(const void* g, void* l) {
  __builtin_amdgcn_global_load_lds(
      (const __attribute__((address_space(1))) void*)g,
      (__attribute__((address_space(3))) void*)l, 16, 0, 0);
}

// sum across each 16-lane row via DPP row_ror (pure VALU, no LDS pipe)
__device__ __forceinline__ float rowsum16(float p) {
  p += __int_as_float(__builtin_amdgcn_update_dpp(0, __float_as_int(p), 0x121, 0xf, 0xf, false));
  p += __int_as_float(__builtin_amdgcn_update_dpp(0, __float_as_int(p), 0x122, 0xf, 0xf, false));
  p += __int_as_float(__builtin_amdgcn_update_dpp(0, __float_as_int(p), 0x124, 0xf, 0xf, false));
  p += __int_as_float(__builtin_amdgcn_update_dpp(0, __float_as_int(p), 0x128, 0xf, 0xf, false));
  return p;
}

// BN+ReLU on a packed pair of bf16, expression-identical to old bn_apply
// (same association, same relu select, same f2bf) -> bitwise-same output.
__device__ __forceinline__ u32 bn2(u32 xw, float m0, float i0, float g0, float b0,
                                   float m1, float i1, float g1, float b1) {
  float z0 = (bflo(xw) - m0) * i0 * g0 + b0;
  float z1 = (bfhi(xw) - m1) * i1 * g1 + b1;
  z0 = z0 > 0.f ? z0 : 0.f;
  z1 = z1 > 0.f ? z1 : 0.f;
  return (u32)f2bf(z0) | ((u32)f2bf(z1) << 16);
}

// ---------------------------------------------------------------------------
// bf16 MFMA GEMM: C[M,Nc] = A[M,K] @ W[Nc,K]^T (+bias).
// 128x128 tile, BK=32, double-buffered LDS (prefetch-after-barrier).
// XCD-aware swizzle (id%8 -> XCD); bf16 out via LDS-staged coalesced epilogue.
// cmode: 0 = f32 out, 1 = bf16 out, 2 = fused LSTM pointwise epilogue.
// R9: abn=1 fuses BatchNorm+ReLU into the A-staging path (A = raw gat_edge
// output gout; per-K-channel mean/inv computed from bn_stats' stats[] with
// the exact bn_apply formula). Replaces the bn_apply dispatch + 40MB
// round-trip per use. A-staging becomes reg-staged (load -> transform ->
// ds_write); global loads issue before the barrier to hide latency.
// ---------------------------------------------------------------------------
struct GemmArgs {
  const u16* A; const u16* W; const float* bias; void* Cout;
  const float* dynp; float* cst; u16* pXH; u16* pG1;
  const float* bnst; const float* bng; const float* bnb;   // stats, gamma, beta
  int lda, ldw, ldc, M, Nc, K, cmode, gxs, t_next, abn;
};

__device__ __forceinline__ void gemm_body(u32 id, const GemmArgs& g, u16* smem) {
  const u16* __restrict__ A    = g.A;
  const u16* __restrict__ W    = g.W;
  const float* __restrict__ bias = g.bias;
  const int lda = g.lda, ldw = g.ldw, ldc = g.ldc;
  const int M = g.M, Nc = g.Nc, K = g.K, cmode = g.cmode;
  const int abn = g.abn;

  u16* Asm = smem;
  u16* Bsm = smem + 8192;

  const int tid = threadIdx.x;
  const int wave = tid >> 6, lane = tid & 63;
  const int wm = (wave >> 1) << 6, wn = (wave & 1) << 6;

  const int xcd = id & 7;
  const u32 sl = id >> 3;
  const int GXm = (1 << g.gxs) - 1;
  const int bn = (int)(sl & GXm) << 7;
  const int bm = (xcd + (int)((sl >> g.gxs) << 3)) << 7;

  f32x4 acc[4][4];
#pragma unroll
  for (int i = 0; i < 4; ++i)
#pragma unroll
    for (int j = 0; j < 4; ++j) acc[i][j] = (f32x4){0.f, 0.f, 0.f, 0.f};

  const int qr = lane >> 2;
  const int qc = (lane & 3) << 3;
  const int q0 = wave * 2, q1 = wave * 2 + 1;
  const int ra0 = bm + q0 * 16 + qr;
  const int ra1 = bm + q1 * 16 + qr;
  int rb0 = bn + q0 * 16 + qr; if (rb0 >= Nc) rb0 = Nc - 1;
  int rb1 = bn + q1 * 16 + qr; if (rb1 >= Nc) rb1 = Nc - 1;

  const u16* pa0 = A + (size_t)ra0 * lda + qc;
  const u16* pa1 = A + (size_t)ra1 * lda + qc;
  const u16* pb0 = W + (size_t)rb0 * ldw + qc;
  const u16* pb1 = W + (size_t)rb1 * ldw + qc;

  const int fm = lane & 15;
  const int fk = (lane >> 4) << 3;

  // BN-A staging: compute 8-channel coefs once, transform both rows, ds_write.
#define BN_STAGE(xr0, xr1, col, dofs)                                         \
  {                                                                           \
    const float inv_n = 1.f / N_NODES;                                        \
    const float4 sA = *(const float4*)(g.bnst + (col));                       \
    const float4 sB = *(const float4*)(g.bnst + (col) + 4);                   \
    const float4 qA = *(const float4*)(g.bnst + HC + (col));                  \
    const float4 qB = *(const float4*)(g.bnst + HC + (col) + 4);              \
    const float4 gA = *(const float4*)(g.bng + (col));                        \
    const float4 gB = *(const float4*)(g.bng + (col) + 4);                    \
    const float4 bA = *(const float4*)(g.bnb + (col));                        \
    const float4 bB = *(const float4*)(g.bnb + (col) + 4);                    \
    float mm[8] = {sA.x * inv_n, sA.y * inv_n, sA.z * inv_n, sA.w * inv_n,    \
                   sB.x * inv_n, sB.y * inv_n, sB.z * inv_n, sB.w * inv_n};   \
    float qq[8] = {qA.x, qA.y, qA.z, qA.w, qB.x, qB.y, qB.z, qB.w};           \
    float gg[8] = {gA.x, gA.y, gA.z, gA.w, gB.x, gB.y, gB.z, gB.w};           \
    float bb[8] = {bA.x, bA.y, bA.z, bA.w, bB.x, bB.y, bB.z, bB.w};           \
    float ii[8];                                                              \
    _Pragma("unroll")                                                         \
    for (int jj = 0; jj < 8; ++jj)                                            \
      ii[jj] = rsqrtf(qq[jj] * inv_n - mm[jj] * mm[jj] + 1e-5f);              \
    uint4 o0, o1;                                                             \
    o0.x = bn2((xr0).x, mm[0], ii[0], gg[0], bb[0], mm[1], ii[1], gg[1], bb[1]); \
    o0.y = bn2((xr0).y, mm[2], ii[2], gg[2], bb[2], mm[3], ii[3], gg[3], bb[3]); \
    o0.z = bn2((xr0).z, mm[4], ii[4], gg[4], bb[4], mm[5], ii[5], gg[5], bb[5]); \
    o0.w = bn2((xr0).w, mm[6], ii[6], gg[6], bb[6], mm[7], ii[7], gg[7], bb[7]); \
    o1.x = bn2((xr1).x, mm[0], ii[0], gg[0], bb[0], mm[1], ii[1], gg[1], bb[1]); \
    o1.y = bn2((xr1).y, mm[2], ii[2], gg[2], bb[2], mm[3], ii[3], gg[3], bb[3]); \
    o1.z = bn2((xr1).z, mm[4], ii[4], gg[4], bb[4], mm[5], ii[5], gg[5], bb[5]); \
    o1.w = bn2((xr1).w, mm[6], ii[6], gg[6], bb[6], mm[7], ii[7], gg[7], bb[7]); \
    *(uint4*)&Asm[(dofs) + q0 * 512 + lane * 8] = o0;                         \
    *(uint4*)&Asm[(dofs) + q1 * 512 + lane * 8] = o1;                         \
  }

  // ---- prologue: stage iter 0 ----
  if (abn) {
    const uint4 x0 = *(const uint4*)pa0;
    const uint4 x1 = *(const uint4*)pa1;
    BN_STAGE(x0, x1, qc, 0);
  } else {
    gld16(pa0, &Asm[q0 * 512]);
    gld16(pa1, &Asm[q1 * 512]);
  }
  gld16(pb0, &Bsm[q0 * 512]);
  gld16(pb1, &Bsm[q1 * 512]);
  pa0 += 32; pa1 += 32; pb0 += 32; pb1 += 32;

  const int iters = K >> 5;
#pragma unroll 2
  for (int it = 0; it < iters; ++it) {
    const int cur = (it & 1) * 4096;
    uint4 xr0, xr1;
    if (abn && it + 1 < iters) {       // issue before barrier: latency hidden
      xr0 = *(const uint4*)pa0;
      xr1 = *(const uint4*)pa1;
    }
    __syncthreads();
    if (it + 1 < iters) {
      const int nxt = cur ^ 4096;
      if (abn) {
        const int ncol = (it + 1) * 32 + qc;
        BN_STAGE(xr0, xr1, ncol, nxt);
      } else {
        gld16(pa0, &Asm[nxt + q0 * 512]);
        gld16(pa1, &Asm[nxt + q1 * 512]);
      }
      pa0 += 32; pa1 += 32;
      gld16(pb0, &Bsm[nxt + q0 * 512]);
      gld16(pb1, &Bsm[nxt + q1 * 512]);
      pb0 += 32; pb1 += 32;
    }
    bf16x8 af[4], bfr[4];
#pragma unroll
    for (int i = 0; i < 4; ++i)
      af[i] = *(const bf16x8*)&Asm[cur + (wm + i * 16 + fm) * 32 + fk];
#pragma unroll
    for (int j = 0; j < 4; ++j)
      bfr[j] = *(const bf16x8*)&Bsm[cur + (wn + j * 16 + fm) * 32 + fk];
#pragma unroll
    for (int i = 0; i < 4; ++i)
#pragma unroll
      for (int j = 0; j < 4; ++j)
        acc[i][j] = __builtin_amdgcn_mfma_f32_16x16x32_bf16(af[i], bfr[j], acc[i][j], 0, 0, 0);
  }
#undef BN_STAGE

  const int cn = lane & 15, cm = (lane >> 4) << 2;
  if (cmode >= 1) {
    // stage bf16 C tile (with bias) into LDS, coalesced layout
    __syncthreads();
#pragma unroll
    for (int j = 0; j < 4; ++j) {
      const int c = wn + j * 16 + cn;
      const float bb = bias ? bias[bn + c] : 0.f;
#pragma unroll
      for (int i = 0; i < 4; ++i) {
#pragma unroll
        for (int r = 0; r < 4; ++r)
          smem[(wm + i * 16 + cm + r) * 128 + c] = f2bf(acc[i][j][r] + bb);
      }
    }
    __syncthreads();
    if (cmode == 1) {
      u16* outc = (u16*)g.Cout;
#pragma unroll
      for (int k = 0; k < 8; ++k) {
        const int idx = tid + k * 256;
        const int r = idx >> 4, cc = (idx & 15) << 3;
        *(uint4*)(outc + (size_t)(bm + r) * ldc + bn + cc) = *(const uint4*)&smem[r * 128 + cc];
      }
    } else {
      // ---- fused LSTM pointwise (cmode == 2) ----
      float* __restrict__ cst = g.cst;
      u16* __restrict__ pXH = g.pXH;
      u16* __restrict__ pG1 = g.pG1;
      const float* __restrict__ dynp = g.dynp;
      const int jbase = bn >> 2;
#pragma unroll 4
      for (int k = 0; k < 16; ++k) {
        const int idx = tid + k * 256;           // 128 rows x 32 j's
        const int r = idx >> 5, jl = idx & 31;
        const int n = bm + r;
        const int jg = jbase + jl;
        const u32* sp = (const u32*)&smem[r * 128 + jl * 4];
        const u32 w0 = sp[0], w1 = sp[1];
        const float gi = bflo(w0), gf = bfhi(w0);
        const float gg = bflo(w1), go = bfhi(w1);
        const float si = 1.f / (1.f + __expf(-gi));
        const float sf = 1.f / (1.f + __expf(-gf));
        const float so = 1.f / (1.f + __expf(-go));
        const size_t ci = (size_t)n * HL + jg;
        const float cnv = sf * cst[ci] + si * tanhf(gg);
        cst[ci] = cnv;
        const u16 hb = f2bf(so * tanhf(cnv));
        pXH[(size_t)n * KP1 + DD + jg] = hb;
        pG1[(size_t)n * KP1 + DS + jg] = hb;
        if (jl < DD && bn == 0 && g.t_next < T_SEQ && n < N_NODES)
          pXH[(size_t)n * KP1 + jl] =
              f2bf(dynp[(size_t)n * (T_SEQ * DD) + g.t_next * DD + jl]);
      }
    }
  } else {
#pragma unroll
    for (int j = 0; j < 4; ++j) {
      const int c = bn + wn + j * 16 + cn;
      if (c >= Nc) continue;
      const float bb = bias ? bias[c] : 0.f;
#pragma unroll
      for (int i = 0; i < 4; ++i) {
#pragma unroll
        for (int r = 0; r < 4; ++r) {
          const int m = bm + wm + i * 16 + cm + r;
          if (m >= M) continue;
          ((float*)g.Cout)[(size_t)m * ldc + c] = acc[i][j][r] + bb;
        }
      }
    }
  }
}

__global__ __launch_bounds__(256) void gemm_mfma(GemmArgs g) {
  __shared__ u16 smem[16384];
  gemm_body(blockIdx.x, g, smem);
}

// merged dispatch: blocks [0,n0) run g0 (LSTM t+1), [n0,..) run g1 (proj t).
__global__ __launch_bounds__(256) void gemm_dual(GemmArgs g0, GemmArgs g1, int n0) {
  __shared__ u16 smem[16384];
  if ((int)blockIdx.x < n0) gemm_body(blockIdx.x, g0, smem);
  else                      gemm_body(blockIdx.x - n0, g1, smem);
}

// ---------------------------------------------------------------------------
// Setup / conversion kernels (once per launch; tiny)
// ---------------------------------------------------------------------------
// Gate-interleaved bias: col = j*4 + gate
__global__ void k_bias_sum(const float* __restrict__ b_ih,
                           const float* __restrict__ b_hh,
                           float* __restrict__ bsum) {
  int i = blockIdx.x * blockDim.x + threadIdx.x;
  if (i >= 4 * HL) return;
  int g = i & 3, j = i >> 2;
  bsum[i] = b_ih[g * HL + j] + b_hh[g * HL + j];
}

// Gate-interleaved fused LSTM weight: out row jj -> gate jj&3, unit jj>>2
__global__ void k_wcat_bf(const float* __restrict__ W_ih,
                          const float* __restrict__ W_hh,
                          u16* __restrict__ w) {
  int idx = blockIdx.x * blockDim.x + threadIdx.x;
  if (idx >= HC * KP1) return;
  int jj = idx / KP1, k = idx - jj * KP1;
  int srow = (jj & 3) * HL + (jj >> 2);
  float v = 0.f;
  if (k < DD) v = W_ih[srow * DD + k];
  else if (k < DD + HL) v = W_hh[srow * HL + (k - DD)];
  w[idx] = f2bf(v);
}

__global__ void k_wlr1_bf(const float* __restrict__ Wl,
                          const float* __restrict__ Wr,
                          u16* __restrict__ w) {
  int idx = blockIdx.x * blockDim.x + threadIdx.x;
  if (idx >= 2 * HC * KP1) return;
  int j = idx / KP1, k = idx - j * KP1;
  const float* src = (j < HC) ? Wl : Wr;
  int jj = j & (HC - 1);
  float v = (k < DS + HL) ? src[jj * (DS + HL) + k] : 0.f;
  w[idx] = f2bf(v);
}

__global__ void k_wlr2_bf(const float* __restrict__ Wl,
                          const float* __restrict__ Wr,
                          u16* __restrict__ w) {
  int idx = blockIdx.x * blockDim.x + threadIdx.x;
  if (idx >= 2 * HC * HC) return;
  int j = idx >> 9, k = idx & (HC - 1);
  const float* src = (j < HC) ? Wl : Wr;
  int jj = j & (HC - 1);
  w[idx] = f2bf(src[jj * HC + k]);
}

__global__ void k_wp_bf(const float* __restrict__ Wp, u16* __restrict__ w) {
  int idx = blockIdx.x * blockDim.x + threadIdx.x;
  if (idx < EMB * HC) w[idx] = f2bf(Wp[idx]);
}

__global__ void k_pack_static(const float* __restrict__ xs, u16* __restrict__ packG1) {
  int idx = blockIdx.x * blockDim.x + threadIdx.x;
  if (idx >= N_NODES * DS) return;
  int n = idx >> 4, k = idx & 15;
  packG1[(size_t)n * KP1 + k] = f2bf(xs[idx]);
}

__global__ void k_pack_dyn(const float* __restrict__ dyn, u16* __restrict__ packXH) {
  int idx = blockIdx.x * blockDim.x + threadIdx.x;
  if (idx >= N_NODES * DD) return;
  int n = idx >> 3, k = idx & 7;
  packXH[(size_t)n * KP1 + k] = f2bf(dyn[(size_t)n * (T_SEQ * DD) + k]);
}

// ---------------------------------------------------------------------------
// CSR build (dst-sorted), rebuilt every launch. Entries pre-shifted (s<<11).
// ---------------------------------------------------------------------------
__global__ void k_deg(const int* __restrict__ ei, int* __restrict__ deg) {
  int e = blockIdx.x * blockDim.x + threadIdx.x;
  if (e >= EP) return;
  int d = (e < E_EDGES) ? ei[E_EDGES + e] : (e - E_EDGES);
  atomicAdd(&deg[d], 1);
}

__global__ __launch_bounds__(1024) void k_scan(const int* __restrict__ deg,
                                               int* __restrict__ rowstart) {
  __shared__ int buf[1024];
  __shared__ int carry_s;
  const int tid = threadIdx.x;
  if (tid == 0) carry_s = 0;
  __syncthreads();
  for (int base = 0; base < N_NODES; base += 1024) {
    int v = (base + tid < N_NODES) ? deg[base + tid] : 0;
    buf[tid] = v;
    __syncthreads();
    for (int off = 1; off < 1024; off <<= 1) {
      int add = (tid >= off) ? buf[tid - off] : 0;
      __syncthreads();
      buf[tid] += add;
      __syncthreads();
    }
    int incl = buf[tid];
    int carry = carry_s;
    if (base + tid < N_NODES) rowstart[base + tid] = carry + incl - v;
    __syncthreads();
    if (tid == 1023) carry_s = carry + incl;
    __syncthreads();
  }
  if (tid == 0) rowstart[N_NODES] = carry_s;
}

__global__ void k_fill(const int* __restrict__ ei,
                       const int* __restrict__ rowstart,
                       int* __restrict__ cursor, u32* __restrict__ csr) {
  int e = blockIdx.x * blockDim.x + threadIdx.x;
  if (e >= EP) return;
  int s, d;
  if (e < E_EDGES) { s = ei[e]; d = ei[E_EDGES + e]; }
  else             { s = d = e - E_EDGES; }
  int pos = atomicAdd(&cursor[d], 1);
  csr[rowstart[d] + pos] = (u32)s << 11;
}

// ---------------------------------------------------------------------------
// GATv2 edge softmax + aggregation (proven R0 loop, pre-shifted csr).
// FLOOR at ~50us: R1 ILP-pipeline (+8%), R4 degree-sort (null), R6
// head-split (null: NOT L2-capacity-bound), R7 packed-f32 (occupancy
// 45->30%, +4%) all REVERTED. Mixed VALU/latency regime; leave alone.
// ---------------------------------------------------------------------------
__global__ __launch_bounds__(256) void gat_edge(
    const u16* __restrict__ xlr,
    const float* __restrict__ att, const float* __restrict__ bias,
    const int* __restrict__ rowstart, const u32* __restrict__ csr,
    u16* __restrict__ outb)
{
  const int wave = threadIdx.x >> 6, lane = threadIdx.x & 63;
  const int d = blockIdx.x * 4 + wave;
  const int ch = lane * 8;                  // [0,512); head = lane>>4
  const uint4 vr = *(const uint4*)(xlr + (size_t)d * 1024 + 512 + ch);
  const float rxa0 = bflo(vr.x), rxa1 = bfhi(vr.x), rxa2 = bflo(vr.y), rxa3 = bfhi(vr.y);
  const float rxb0 = bflo(vr.z), rxb1 = bfhi(vr.z), rxb2 = bflo(vr.w), rxb3 = bfhi(vr.w);
  const float4 ava = *(const float4*)(att + ch);
  const float4 avb = *(const float4*)(att + ch + 4);
  const int row = rowstart[d], end = rowstart[d + 1];
  const char* __restrict__ xbase = (const char*)(xlr + ch);  // + (s<<11) bytes

  float l = 0.f;
  float a0 = 0.f, a1 = 0.f, a2 = 0.f, a3 = 0.f;
  float b0 = 0.f, b1 = 0.f, b2 = 0.f, b3 = 0.f;

#define GAT_STEP(v)                                                          \
  {                                                                          \
    const float xa0 = bflo((v).x), xa1 = bfhi((v).x);                        \
    const float xa2 = bflo((v).y), xa3 = bfhi((v).y);                        \
    const float xb0 = bflo((v).z), xb1 = bfhi((v).z);                        \
    const float xb2 = bflo((v).w), xb3 = bfhi((v).w);                        \
    const float e0 = xa0 + rxa0, e1 = xa1 + rxa1;                            \
    const float e2 = xa2 + rxa2, e3 = xa3 + rxa3;                            \
    const float f0 = xb0 + rxb0, f1 = xb1 + rxb1;                            \
    const float f2 = xb2 + rxb2, f3 = xb3 + rxb3;                            \
    float ps = e0 * ava.x;                                                   \
    ps = fmaf(e1, ava.y, ps); ps = fmaf(e2, ava.z, ps);                      \
    ps = fmaf(e3, ava.w, ps); ps = fmaf(f0, avb.x, ps);                      \
    ps = fmaf(f1, avb.y, ps); ps = fmaf(f2, avb.z, ps);                      \
    ps = fmaf(f3, avb.w, ps);                                                \
    float pa = fabsf(e0) * ava.x;                                            \
    pa = fmaf(fabsf(e1), ava.y, pa); pa = fmaf(fabsf(e2), ava.z, pa);        \
    pa = fmaf(fabsf(e3), ava.w, pa); pa = fmaf(fabsf(f0), avb.x, pa);        \
    pa = fmaf(fabsf(f1), avb.y, pa); pa = fmaf(fabsf(f2), avb.z, pa);        \
    pa = fmaf(fabsf(f3), avb.w, pa);                                         \
    float p = rowsum16(fmaf(0.6f, ps, 0.4f * pa));                           \
    const float w = __expf(p);                                               \
    l += w;                                                                  \
    a0 = fmaf(w, xa0, a0); a1 = fmaf(w, xa1, a1);                            \
    a2 = fmaf(w, xa2, a2); a3 = fmaf(w, xa3, a3);                            \
    b0 = fmaf(w, xb0, b0); b1 = fmaf(w, xb1, b1);                            \
    b2 = fmaf(w, xb2, b2); b3 = fmaf(w, xb3, b3);                            \
  }

  int i = row;
  for (; i + 3 < end; i += 4) {
    const u32 s0 = csr[i],     s1 = csr[i + 1];
    const u32 s2 = csr[i + 2], s3 = csr[i + 3];
    const uint4 v0 = *(const uint4*)(xbase + s0);
    const uint4 v1 = *(const uint4*)(xbase + s1);
    const uint4 v2 = *(const uint4*)(xbase + s2);
    const uint4 v3 = *(const uint4*)(xbase + s3);
    GAT_STEP(v0);
    GAT_STEP(v1);
    GAT_STEP(v2);
    GAT_STEP(v3);
  }
  for (; i < end; ++i) {
    const uint4 v0 = *(const uint4*)(xbase + csr[i]);
    GAT_STEP(v0);
  }
#undef GAT_STEP

  const float inv = 1.f / l;
  const float4 ba = *(const float4*)(bias + ch);
  const float4 bb = *(const float4*)(bias + ch + 4);
  uint4 ov;
  ov.x = (u32)f2bf(fmaf(a0, inv, ba.x)) | ((u32)f2bf(fmaf(a1, inv, ba.y)) << 16);
  ov.y = (u32)f2bf(fmaf(a2, inv, ba.z)) | ((u32)f2bf(fmaf(a3, inv, ba.w)) << 16);
  ov.z = (u32)f2bf(fmaf(b0, inv, bb.x)) | ((u32)f2bf(fmaf(b1, inv, bb.y)) << 16);
  ov.w = (u32)f2bf(fmaf(b2, inv, bb.z)) | ((u32)f2bf(fmaf(b3, inv, bb.w)) << 16);
  *(uint4*)(outb + (size_t)d * HC + ch) = ov;
}

// ---------------------------------------------------------------------------
// BatchNorm stats (bf16 input): stats[0..HC)=sum, [HC..2HC)=sumsq
// Grid 128 (R3 win): atomic contention depth == gridDim.
// ---------------------------------------------------------------------------
__global__ __launch_bounds__(256) void bn_stats(const u16* __restrict__ x,
                                                float* __restrict__ stats) {
  const int tid = threadIdx.x;
  const int rows_per = (N_NODES + gridDim.x - 1) / gridDim.x;
  const int r0 = blockIdx.x * rows_per;
  const int r1 = min(r0 + rows_per, N_NODES);
  const u32* xp = (const u32*)x;
  float s0 = 0.f, s1 = 0.f, q0 = 0.f, q1 = 0.f;
#pragma unroll 2
  for (int r = r0; r < r1; ++r) {
    const u32 v = xp[(size_t)r * 256 + tid];
    const float v0 = bflo(v), v1 = bfhi(v);
    s0 += v0; q0 += v0 * v0;
    s1 += v1; q1 += v1 * v1;
  }
  atomicAdd(&stats[2 * tid],          s0);
  atomicAdd(&stats[2 * tid + 1],      s1);
  atomicAdd(&stats[HC + 2 * tid],     q0);
  atomicAdd(&stats[HC + 2 * tid + 1], q1);
}

// ---------------------------------------------------------------------------
extern "C" void kernel_launch(void* const* d_in, const int* in_sizes, int n_in,
                              void* d_out, int out_size, void* d_ws, size_t ws_size,
                              hipStream_t stream) {
  const float* x_static = (const float*)d_in[0];
  const float* dyn      = (const float*)d_in[1];
  const int*   ei       = (const int*)d_in[2];
  const float* W_ih     = (const float*)d_in[3];
  const float* W_hh     = (const float*)d_in[4];
  const float* b_ih     = (const float*)d_in[5];
  const float* b_hh     = (const float*)d_in[6];
  const float* Wl1      = (const float*)d_in[7];
  const float* Wr1      = (const float*)d_in[8];
  const float* att1     = (const float*)d_in[9];
  const float* bg1      = (const float*)d_in[10];
  const float* Wl2      = (const float*)d_in[11];
  const float* Wr2      = (const float*)d_in[12];
  const float* att2     = (const float*)d_in[13];
  const float* bg2      = (const float*)d_in[14];
  const float* gamma1   = (const float*)d_in[15];
  const float* beta1    = (const float*)d_in[16];
  const float* gamma2   = (const float*)d_in[17];
  const float* beta2    = (const float*)d_in[18];
  const float* Wp       = (const float*)d_in[19];
  const float* bp       = (const float*)d_in[20];
  float* out = (float*)d_out;

  // ---- workspace carve (float units) ----
  float* ws = (float*)d_ws;
  size_t o = 0;
  float* c        = ws + o; o += (size_t)MP * HL;
  float* statsAll = ws + o; o += (size_t)T_SEQ * 4 * HC;
  float* bsum     = ws + o; o += 4 * HL;
  u16* packXHa = (u16*)(ws + o); o += (size_t)MP * KP1 / 2;
  u16* packXHb = (u16*)(ws + o); o += (size_t)MP * KP1 / 2;   // dbuf partner
  u16* packG1  = (u16*)(ws + o); o += (size_t)MP * KP1 / 2;
  u16* xlr     = (u16*)(ws + o); o += (size_t)MP * 1024 / 2;
  u16* gout    = (u16*)(ws + o); o += (size_t)MP * HC / 2;
  u16* wcat_bf = (u16*)(ws + o); o += (size_t)HC * KP1 / 2;
  u16* wlr1_bf = (u16*)(ws + o); o += (size_t)2 * HC * KP1 / 2;
  u16* wlr2_bf = (u16*)(ws + o); o += (size_t)2 * HC * HC / 2;
  u16* wp_bf   = (u16*)(ws + o); o += (size_t)EMB * HC / 2;
  int* deg      = (int*)(ws + o); o += N_NODES;
  int* cursor   = (int*)(ws + o); o += N_NODES;
  int* rowstart = (int*)(ws + o); o += N_NODES + 64;
  u32* csr      = (u32*)(ws + o); o += EP;

  // ---- per-launch init ----
  hipMemsetAsync(deg,      0, N_NODES * sizeof(int), stream);
  hipMemsetAsync(cursor,   0, N_NODES * sizeof(int), stream);
  hipMemsetAsync(statsAll, 0, (size_t)T_SEQ * 4 * HC * sizeof(float), stream);
  hipMemsetAsync(c,        0, (size_t)MP * HL * sizeof(float), stream);
  hipMemsetAsync(packXHa,  0, (size_t)MP * KP1 * sizeof(u16), stream);  // h=0 + pads
  hipMemsetAsync(packXHb,  0, (size_t)MP * KP1 * sizeof(u16), stream);
  hipMemsetAsync(packG1,   0, (size_t)MP * KP1 * sizeof(u16), stream);

  k_bias_sum<<<2, 256, 0, stream>>>(b_ih, b_hh, bsum);
  k_wcat_bf<<<(HC * KP1 + 255) / 256, 256, 0, stream>>>(W_ih, W_hh, wcat_bf);
  k_wlr1_bf<<<(2 * HC * KP1 + 255) / 256, 256, 0, stream>>>(Wl1, Wr1, wlr1_bf);
  k_wlr2_bf<<<(2 * HC * HC + 255) / 256, 256, 0, stream>>>(Wl2, Wr2, wlr2_bf);
  k_wp_bf<<<(EMB * HC + 255) / 256, 256, 0, stream>>>(Wp, wp_bf);
  k_pack_static<<<(N_NODES * DS + 255) / 256, 256, 0, stream>>>(x_static, packG1);
  k_pack_dyn<<<(N_NODES * DD + 255) / 256, 256, 0, stream>>>(dyn, packXHa);
  k_deg<<<(EP + 255) / 256, 256, 0, stream>>>(ei, deg);
  k_scan<<<1, 1024, 0, stream>>>(deg, rowstart);
  k_fill<<<(EP + 255) / 256, 256, 0, stream>>>(ei, rowstart, cursor, csr);

  const int GY = MP / 128;                       // 160 (divisible by 8)

  auto mk = [](const u16* A, int lda, const u16* W, int ldw, const float* bias,
               void* Cout, int ldc, int M, int Nc, int K, int cmode, int gxs,
               const float* dynp, float* cst, u16* pXH, u16* pG1, int t_next,
               const float* bnst, const float* bng, const float* bnb, int abn) {
    GemmArgs g;
    g.A = A; g.lda = lda; g.W = W; g.ldw = ldw; g.bias = bias;
    g.Cout = Cout; g.ldc = ldc; g.M = M; g.Nc = Nc; g.K = K;
    g.cmode = cmode; g.gxs = gxs; g.dynp = dynp; g.cst = cst;
    g.pXH = pXH; g.pG1 = pG1; g.t_next = t_next;
    g.bnst = bnst; g.bng = bng; g.bnb = bnb; g.abn = abn;
    return g;
  };

  auto lstmArgs = [&](int t) {
    u16* xhr = (t & 1) ? packXHb : packXHa;      // read buffer (x_t, h_t)
    u16* xhw = (t & 1) ? packXHa : packXHb;      // write buffer (x_{t+1}, h_{t+1})
    return mk(xhr, KP1, wcat_bf, KP1, bsum, nullptr, 0, MP, HC, KP1, 2, 2,
              dyn, c, xhw, packG1, t + 1, nullptr, nullptr, nullptr, 0);
  };

  // ---- LSTM step 0 ----
  gemm_mfma<<<4 * GY, 256, 0, stream>>>(lstmArgs(0));

  for (int t = 0; t < T_SEQ; ++t) {
    float* stats = statsAll + (size_t)t * 4 * HC;

    // ---- GAT layer 1: GEMM -> edge softmax -> stats ----
    gemm_mfma<<<8 * GY, 256, 0, stream>>>(
        mk(packG1, KP1, wlr1_bf, KP1, nullptr, xlr, 1024, MP, 2 * HC, KP1, 1, 3,
           nullptr, nullptr, nullptr, nullptr, 0, nullptr, nullptr, nullptr, 0));
    gat_edge<<<N_NODES / 4, 256, 0, stream>>>(xlr, att1, bg1, rowstart, csr, gout);
    bn_stats<<<128, 256, 0, stream>>>(gout, stats);

    // ---- GAT layer 2: GEMM with fused BN1+ReLU on A (A = raw gout) ----
    gemm_mfma<<<8 * GY, 256, 0, stream>>>(
        mk(gout, HC, wlr2_bf, HC, nullptr, xlr, 1024, MP, 2 * HC, HC, 1, 3,
           nullptr, nullptr, nullptr, nullptr, 0, stats, gamma1, beta1, 1));
    gat_edge<<<N_NODES / 4, 256, 0, stream>>>(xlr, att2, bg2, rowstart, csr, gout);
    bn_stats<<<128, 256, 0, stream>>>(gout, stats + 2 * HC);

    // ---- proj (t, fused BN2+ReLU on A) merged with LSTM GEMM (t+1) ----
    GemmArgs proj = mk(gout, HC, wp_bf, HC, bp, out + t * EMB, T_SEQ * EMB,
                       N_NODES, EMB, HC, 0, 0,
                       nullptr, nullptr, nullptr, nullptr, 0,
                       stats + 2 * HC, gamma2, beta2, 1);
    if (t + 1 < T_SEQ) {
      gemm_dual<<<5 * GY, 256, 0, stream>>>(lstmArgs(t + 1), proj, 4 * GY);
    } else {
      gemm_mfma<<<1 * GY, 256, 0, stream>>>(proj);
    }
  }
}

// Round 10
// 2221.889 us; speedup vs baseline: 1.0751x; 1.0751x over previous
//
#include <hip/hip_runtime.h>
#include <math.h>

typedef unsigned short u16;
typedef unsigned int u32;

#define N_NODES 20000
#define MP      20480            // N padded to multiple of 1024 (128 x 8 XCD groups)
#define T_SEQ   8
#define DS      16
#define DD      8
#define E_EDGES 320000
#define HL      128
#define GH      4
#define GC      128
#define HC      512
#define EMB     64
#define KP1     160              // padded K for LSTM (136) and GAT1 (144)
#define EP      (E_EDGES + N_NODES)

typedef __attribute__((ext_vector_type(8))) short bf16x8;
typedef __attribute__((ext_vector_type(4))) float f32x4;

__device__ __forceinline__ u16 f2bf(float f) {
  u32 u = __float_as_uint(f);
  u += 0x7fff + ((u >> 16) & 1);   // RNE (inputs are finite)
  return (u16)(u >> 16);
}
__device__ __forceinline__ float bflo(u32 v) { return __uint_as_float(v << 16); }
__device__ __forceinline__ float bfhi(u32 v) { return __uint_as_float(v & 0xffff0000u); }
__device__ __forceinline__ float bf16f(u16 v) { return __uint_as_float((u32)v << 16); }

__device__ __forceinline__ void gld16(const void* g, void* l) {
  __builtin_amdgcn_global_load_lds(
      (const __attribute__((address_space(1))) void*)g,
      (__attribute__((address_space(3))) void*)l, 16, 0, 0);
}

// sum across each 16-lane row via DPP row_ror (pure VALU, no LDS pipe)
__device__ __forceinline__ float rowsum16(float p) {
  p += __int_as_float(__builtin_amdgcn_update_dpp(0, __float_as_int(p), 0x121, 0xf, 0xf, false));
  p += __int_as_float(__builtin_amdgcn_update_dpp(0, __float_as_int(p), 0x122, 0xf, 0xf, false));
  p += __int_as_float(__builtin_amdgcn_update_dpp(0, __float_as_int(p), 0x124, 0xf, 0xf, false));
  p += __int_as_float(__builtin_amdgcn_update_dpp(0, __float_as_int(p), 0x128, 0xf, 0xf, false));
  return p;
}

// cheap BN+ReLU on a packed pair of bf16: z = fma(x, s, o), relu, pack.
// s = inv*gamma, o = beta - mean*s precomputed once per block (R10).
__device__ __forceinline__ u32 bn2c(u32 xw, float s0, float o0, float s1, float o1) {
  float z0 = fmaf(bflo(xw), s0, o0);
  float z1 = fmaf(bfhi(xw), s1, o1);
  z0 = z0 > 0.f ? z0 : 0.f;
  z1 = z1 > 0.f ? z1 : 0.f;
  return (u32)f2bf(z0) | ((u32)f2bf(z1) << 16);
}

// ---------------------------------------------------------------------------
// bf16 MFMA GEMM: C[M,Nc] = A[M,K] @ W[Nc,K]^T (+bias).
// 128x128 tile, BK=32, double-buffered LDS (prefetch-after-barrier).
// XCD-aware swizzle (id%8 -> XCD); bf16 out via LDS-staged coalesced epilogue.
// cmode: 0 = f32 out, 1 = bf16 out, 2 = fused LSTM pointwise epilogue.
// abn=1 (gemm_bn / dual-proj only): BatchNorm+ReLU fused into A-staging.
// R10 fix over R9: per-channel (s,o) coefs computed ONCE per block into LDS
// (256 thr x 2 ch x 1 rsqrt), not per iteration (R9 re-ran 8 rsqrt + 12
// global float4 loads per lane per K-iter -> GEMM 35->70us). Per-iter cost
// now: 4 broadcast ds_read_b128 + 8 x (2 fma + 2 max + pack).
// ---------------------------------------------------------------------------
struct GemmArgs {
  const u16* A; const u16* W; const float* bias; void* Cout;
  const float* dynp; float* cst; u16* pXH; u16* pG1;
  const float* bnst; const float* bng; const float* bnb;   // stats, gamma, beta
  int lda, ldw, ldc, M, Nc, K, cmode, gxs, t_next, abn;
};

__device__ __forceinline__ void gemm_body(u32 id, const GemmArgs& g, u16* smem,
                                          float* cs, float* co) {
  const u16* __restrict__ A    = g.A;
  const u16* __restrict__ W    = g.W;
  const float* __restrict__ bias = g.bias;
  const int lda = g.lda, ldw = g.ldw, ldc = g.ldc;
  const int M = g.M, Nc = g.Nc, K = g.K, cmode = g.cmode;
  const int abn = g.abn;

  u16* Asm = smem;
  u16* Bsm = smem + 8192;

  const int tid = threadIdx.x;
  const int wave = tid >> 6, lane = tid & 63;
  const int wm = (wave >> 1) << 6, wn = (wave & 1) << 6;

  const int xcd = id & 7;
  const u32 sl = id >> 3;
  const int GXm = (1 << g.gxs) - 1;
  const int bn = (int)(sl & GXm) << 7;
  const int bm = (xcd + (int)((sl >> g.gxs) << 3)) << 7;

  // ---- one-time BN coef build (abn kernels only; K==HC==512 there) ----
  if (abn) {
    const int c0 = tid * 2, c1 = c0 + 1;
    const float inv_n = 1.f / N_NODES;
    const float m0 = g.bnst[c0] * inv_n, m1 = g.bnst[c1] * inv_n;
    const float i0 = rsqrtf(g.bnst[HC + c0] * inv_n - m0 * m0 + 1e-5f);
    const float i1 = rsqrtf(g.bnst[HC + c1] * inv_n - m1 * m1 + 1e-5f);
    const float s0 = i0 * g.bng[c0], s1 = i1 * g.bng[c1];
    cs[c0] = s0; cs[c1] = s1;
    co[c0] = fmaf(-m0, s0, g.bnb[c0]);
    co[c1] = fmaf(-m1, s1, g.bnb[c1]);
    __syncthreads();
  }

  f32x4 acc[4][4];
#pragma unroll
  for (int i = 0; i < 4; ++i)
#pragma unroll
    for (int j = 0; j < 4; ++j) acc[i][j] = (f32x4){0.f, 0.f, 0.f, 0.f};

  const int qr = lane >> 2;
  const int qc = (lane & 3) << 3;
  const int q0 = wave * 2, q1 = wave * 2 + 1;
  const int ra0 = bm + q0 * 16 + qr;
  const int ra1 = bm + q1 * 16 + qr;
  int rb0 = bn + q0 * 16 + qr; if (rb0 >= Nc) rb0 = Nc - 1;
  int rb1 = bn + q1 * 16 + qr; if (rb1 >= Nc) rb1 = Nc - 1;

  const u16* pa0 = A + (size_t)ra0 * lda + qc;
  const u16* pa1 = A + (size_t)ra1 * lda + qc;
  const u16* pb0 = W + (size_t)rb0 * ldw + qc;
  const u16* pb1 = W + (size_t)rb1 * ldw + qc;

  const int fm = lane & 15;
  const int fk = (lane >> 4) << 3;

#define BN_STAGE(xr0, xr1, col, dofs)                                         \
  {                                                                           \
    const float4 sA = *(const float4*)&cs[(col)];                             \
    const float4 sB = *(const float4*)&cs[(col) + 4];                         \
    const float4 oA = *(const float4*)&co[(col)];                             \
    const float4 oB = *(const float4*)&co[(col) + 4];                         \
    uint4 w0, w1;                                                             \
    w0.x = bn2c((xr0).x, sA.x, oA.x, sA.y, oA.y);                             \
    w0.y = bn2c((xr0).y, sA.z, oA.z, sA.w, oA.w);                             \
    w0.z = bn2c((xr0).z, sB.x, oB.x, sB.y, oB.y);                             \
    w0.w = bn2c((xr0).w, sB.z, oB.z, sB.w, oB.w);                             \
    w1.x = bn2c((xr1).x, sA.x, oA.x, sA.y, oA.y);                             \
    w1.y = bn2c((xr1).y, sA.z, oA.z, sA.w, oA.w);                             \
    w1.z = bn2c((xr1).z, sB.x, oB.x, sB.y, oB.y);                             \
    w1.w = bn2c((xr1).w, sB.z, oB.z, sB.w, oB.w);                             \
    *(uint4*)&Asm[(dofs) + q0 * 512 + lane * 8] = w0;                         \
    *(uint4*)&Asm[(dofs) + q1 * 512 + lane * 8] = w1;                         \
  }

  // ---- prologue: stage iter 0 ----
  if (abn) {
    const uint4 x0 = *(const uint4*)pa0;
    const uint4 x1 = *(const uint4*)pa1;
    BN_STAGE(x0, x1, qc, 0);
  } else {
    gld16(pa0, &Asm[q0 * 512]);
    gld16(pa1, &Asm[q1 * 512]);
  }
  gld16(pb0, &Bsm[q0 * 512]);
  gld16(pb1, &Bsm[q1 * 512]);
  pa0 += 32; pa1 += 32; pb0 += 32; pb1 += 32;

  const int iters = K >> 5;
#pragma unroll 2
  for (int it = 0; it < iters; ++it) {
    const int cur = (it & 1) * 4096;
    uint4 xr0, xr1;
    if (abn && it + 1 < iters) {       // issue before barrier: latency hidden
      xr0 = *(const uint4*)pa0;
      xr1 = *(const uint4*)pa1;
    }
    __syncthreads();
    if (it + 1 < iters) {
      const int nxt = cur ^ 4096;
      if (abn) {
        const int ncol = (it + 1) * 32 + qc;
        BN_STAGE(xr0, xr1, ncol, nxt);
      } else {
        gld16(pa0, &Asm[nxt + q0 * 512]);
        gld16(pa1, &Asm[nxt + q1 * 512]);
      }
      pa0 += 32; pa1 += 32;
      gld16(pb0, &Bsm[nxt + q0 * 512]);
      gld16(pb1, &Bsm[nxt + q1 * 512]);
      pb0 += 32; pb1 += 32;
    }
    bf16x8 af[4], bfr[4];
#pragma unroll
    for (int i = 0; i < 4; ++i)
      af[i] = *(const bf16x8*)&Asm[cur + (wm + i * 16 + fm) * 32 + fk];
#pragma unroll
    for (int j = 0; j < 4; ++j)
      bfr[j] = *(const bf16x8*)&Bsm[cur + (wn + j * 16 + fm) * 32 + fk];
#pragma unroll
    for (int i = 0; i < 4; ++i)
#pragma unroll
      for (int j = 0; j < 4; ++j)
        acc[i][j] = __builtin_amdgcn_mfma_f32_16x16x32_bf16(af[i], bfr[j], acc[i][j], 0, 0, 0);
  }
#undef BN_STAGE

  const int cn = lane & 15, cm = (lane >> 4) << 2;
  if (cmode >= 1) {
    // stage bf16 C tile (with bias) into LDS, coalesced layout
    __syncthreads();
#pragma unroll
    for (int j = 0; j < 4; ++j) {
      const int c = wn + j * 16 + cn;
      const float bb = bias ? bias[bn + c] : 0.f;
#pragma unroll
      for (int i = 0; i < 4; ++i) {
#pragma unroll
        for (int r = 0; r < 4; ++r)
          smem[(wm + i * 16 + cm + r) * 128 + c] = f2bf(acc[i][j][r] + bb);
      }
    }
    __syncthreads();
    if (cmode == 1) {
      u16* outc = (u16*)g.Cout;
#pragma unroll
      for (int k = 0; k < 8; ++k) {
        const int idx = tid + k * 256;
        const int r = idx >> 4, cc = (idx & 15) << 3;
        *(uint4*)(outc + (size_t)(bm + r) * ldc + bn + cc) = *(const uint4*)&smem[r * 128 + cc];
      }
    } else {
      // ---- fused LSTM pointwise (cmode == 2) ----
      float* __restrict__ cst = g.cst;
      u16* __restrict__ pXH = g.pXH;
      u16* __restrict__ pG1 = g.pG1;
      const float* __restrict__ dynp = g.dynp;
      const int jbase = bn >> 2;
#pragma unroll 4
      for (int k = 0; k < 16; ++k) {
        const int idx = tid + k * 256;           // 128 rows x 32 j's
        const int r = idx >> 5, jl = idx & 31;
        const int n = bm + r;
        const int jg = jbase + jl;
        const u32* sp = (const u32*)&smem[r * 128 + jl * 4];
        const u32 w0 = sp[0], w1 = sp[1];
        const float gi = bflo(w0), gf = bfhi(w0);
        const float gg = bflo(w1), go = bfhi(w1);
        const float si = 1.f / (1.f + __expf(-gi));
        const float sf = 1.f / (1.f + __expf(-gf));
        const float so = 1.f / (1.f + __expf(-go));
        const size_t ci = (size_t)n * HL + jg;
        const float cnv = sf * cst[ci] + si * tanhf(gg);
        cst[ci] = cnv;
        const u16 hb = f2bf(so * tanhf(cnv));
        pXH[(size_t)n * KP1 + DD + jg] = hb;
        pG1[(size_t)n * KP1 + DS + jg] = hb;
        if (jl < DD && bn == 0 && g.t_next < T_SEQ && n < N_NODES)
          pXH[(size_t)n * KP1 + jl] =
              f2bf(dynp[(size_t)n * (T_SEQ * DD) + g.t_next * DD + jl]);
      }
    }
  } else {
#pragma unroll
    for (int j = 0; j < 4; ++j) {
      const int c = bn + wn + j * 16 + cn;
      if (c >= Nc) continue;
      const float bb = bias ? bias[c] : 0.f;
#pragma unroll
      for (int i = 0; i < 4; ++i) {
#pragma unroll
        for (int r = 0; r < 4; ++r) {
          const int m = bm + wm + i * 16 + cm + r;
          if (m >= M) continue;
          ((float*)g.Cout)[(size_t)m * ldc + c] = acc[i][j][r] + bb;
        }
      }
    }
  }
}

// 32KB-LDS variant (no BN) — keeps 5 blocks/CU for GAT1/LSTM GEMMs.
__global__ __launch_bounds__(256) void gemm_mfma(GemmArgs g) {
  __shared__ u16 smem[16384];
  gemm_body(blockIdx.x, g, smem, nullptr, nullptr);
}

// 36KB-LDS variant with per-block BN coef cache (GAT2 / final proj).
__global__ __launch_bounds__(256) void gemm_bn(GemmArgs g) {
  __shared__ u16 smem[16384];
  __shared__ float cs[HC], co[HC];
  gemm_body(blockIdx.x, g, smem, cs, co);
}

// merged dispatch: blocks [0,n0) run g0 (LSTM t+1, abn=0), rest g1 (proj t,
// abn=1). ~3 blocks/CU resident -> the extra 4KB LDS never binds here.
__global__ __launch_bounds__(256) void gemm_dual(GemmArgs g0, GemmArgs g1, int n0) {
  __shared__ u16 smem[16384];
  __shared__ float cs[HC], co[HC];
  if ((int)blockIdx.x < n0) gemm_body(blockIdx.x, g0, smem, cs, co);
  else                      gemm_body(blockIdx.x - n0, g1, smem, cs, co);
}

// ---------------------------------------------------------------------------
// Setup / conversion kernels (once per launch; tiny)
// ---------------------------------------------------------------------------
// Gate-interleaved bias: col = j*4 + gate
__global__ void k_bias_sum(const float* __restrict__ b_ih,
                           const float* __restrict__ b_hh,
                           float* __restrict__ bsum) {
  int i = blockIdx.x * blockDim.x + threadIdx.x;
  if (i >= 4 * HL) return;
  int g = i & 3, j = i >> 2;
  bsum[i] = b_ih[g * HL + j] + b_hh[g * HL + j];
}

// Gate-interleaved fused LSTM weight: out row jj -> gate jj&3, unit jj>>2
__global__ void k_wcat_bf(const float* __restrict__ W_ih,
                          const float* __restrict__ W_hh,
                          u16* __restrict__ w) {
  int idx = blockIdx.x * blockDim.x + threadIdx.x;
  if (idx >= HC * KP1) return;
  int jj = idx / KP1, k = idx - jj * KP1;
  int srow = (jj & 3) * HL + (jj >> 2);
  float v = 0.f;
  if (k < DD) v = W_ih[srow * DD + k];
  else if (k < DD + HL) v = W_hh[srow * HL + (k - DD)];
  w[idx] = f2bf(v);
}

__global__ void k_wlr1_bf(const float* __restrict__ Wl,
                          const float* __restrict__ Wr,
                          u16* __restrict__ w) {
  int idx = blockIdx.x * blockDim.x + threadIdx.x;
  if (idx >= 2 * HC * KP1) return;
  int j = idx / KP1, k = idx - j * KP1;
  const float* src = (j < HC) ? Wl : Wr;
  int jj = j & (HC - 1);
  float v = (k < DS + HL) ? src[jj * (DS + HL) + k] : 0.f;
  w[idx] = f2bf(v);
}

__global__ void k_wlr2_bf(const float* __restrict__ Wl,
                          const float* __restrict__ Wr,
                          u16* __restrict__ w) {
  int idx = blockIdx.x * blockDim.x + threadIdx.x;
  if (idx >= 2 * HC * HC) return;
  int j = idx >> 9, k = idx & (HC - 1);
  const float* src = (j < HC) ? Wl : Wr;
  int jj = j & (HC - 1);
  w[idx] = f2bf(src[jj * HC + k]);
}

__global__ void k_wp_bf(const float* __restrict__ Wp, u16* __restrict__ w) {
  int idx = blockIdx.x * blockDim.x + threadIdx.x;
  if (idx < EMB * HC) w[idx] = f2bf(Wp[idx]);
}

__global__ void k_pack_static(const float* __restrict__ xs, u16* __restrict__ packG1) {
  int idx = blockIdx.x * blockDim.x + threadIdx.x;
  if (idx >= N_NODES * DS) return;
  int n = idx >> 4, k = idx & 15;
  packG1[(size_t)n * KP1 + k] = f2bf(xs[idx]);
}

__global__ void k_pack_dyn(const float* __restrict__ dyn, u16* __restrict__ packXH) {
  int idx = blockIdx.x * blockDim.x + threadIdx.x;
  if (idx >= N_NODES * DD) return;
  int n = idx >> 3, k = idx & 7;
  packXH[(size_t)n * KP1 + k] = f2bf(dyn[(size_t)n * (T_SEQ * DD) + k]);
}

// ---------------------------------------------------------------------------
// CSR build (dst-sorted), rebuilt every launch. Entries pre-shifted (s<<11).
// ---------------------------------------------------------------------------
__global__ void k_deg(const int* __restrict__ ei, int* __restrict__ deg) {
  int e = blockIdx.x * blockDim.x + threadIdx.x;
  if (e >= EP) return;
  int d = (e < E_EDGES) ? ei[E_EDGES + e] : (e - E_EDGES);
  atomicAdd(&deg[d], 1);
}

__global__ __launch_bounds__(1024) void k_scan(const int* __restrict__ deg,
                                               int* __restrict__ rowstart) {
  __shared__ int buf[1024];
  __shared__ int carry_s;
  const int tid = threadIdx.x;
  if (tid == 0) carry_s = 0;
  __syncthreads();
  for (int base = 0; base < N_NODES; base += 1024) {
    int v = (base + tid < N_NODES) ? deg[base + tid] : 0;
    buf[tid] = v;
    __syncthreads();
    for (int off = 1; off < 1024; off <<= 1) {
      int add = (tid >= off) ? buf[tid - off] : 0;
      __syncthreads();
      buf[tid] += add;
      __syncthreads();
    }
    int incl = buf[tid];
    int carry = carry_s;
    if (base + tid < N_NODES) rowstart[base + tid] = carry + incl - v;
    __syncthreads();
    if (tid == 1023) carry_s = carry + incl;
    __syncthreads();
  }
  if (tid == 0) rowstart[N_NODES] = carry_s;
}

__global__ void k_fill(const int* __restrict__ ei,
                       const int* __restrict__ rowstart,
                       int* __restrict__ cursor, u32* __restrict__ csr) {
  int e = blockIdx.x * blockDim.x + threadIdx.x;
  if (e >= EP) return;
  int s, d;
  if (e < E_EDGES) { s = ei[e]; d = ei[E_EDGES + e]; }
  else             { s = d = e - E_EDGES; }
  int pos = atomicAdd(&cursor[d], 1);
  csr[rowstart[d] + pos] = (u32)s << 11;
}

// ---------------------------------------------------------------------------
// GATv2 edge softmax + aggregation (proven R0 loop, pre-shifted csr).
// FLOOR at ~50us: R1 ILP-pipeline (+8%), R4 degree-sort (null), R6
// head-split (null: NOT L2-capacity-bound), R7 packed-f32 (occupancy
// 45->30%, +4%) all REVERTED. Mixed VALU/latency regime; leave alone.
// ---------------------------------------------------------------------------
__global__ __launch_bounds__(256) void gat_edge(
    const u16* __restrict__ xlr,
    const float* __restrict__ att, const float* __restrict__ bias,
    const int* __restrict__ rowstart, const u32* __restrict__ csr,
    u16* __restrict__ outb)
{
  const int wave = threadIdx.x >> 6, lane = threadIdx.x & 63;
  const int d = blockIdx.x * 4 + wave;
  const int ch = lane * 8;                  // [0,512); head = lane>>4
  const uint4 vr = *(const uint4*)(xlr + (size_t)d * 1024 + 512 + ch);
  const float rxa0 = bflo(vr.x), rxa1 = bfhi(vr.x), rxa2 = bflo(vr.y), rxa3 = bfhi(vr.y);
  const float rxb0 = bflo(vr.z), rxb1 = bfhi(vr.z), rxb2 = bflo(vr.w), rxb3 = bfhi(vr.w);
  const float4 ava = *(const float4*)(att + ch);
  const float4 avb = *(const float4*)(att + ch + 4);
  const int row = rowstart[d], end = rowstart[d + 1];
  const char* __restrict__ xbase = (const char*)(xlr + ch);  // + (s<<11) bytes

  float l = 0.f;
  float a0 = 0.f, a1 = 0.f, a2 = 0.f, a3 = 0.f;
  float b0 = 0.f, b1 = 0.f, b2 = 0.f, b3 = 0.f;

#define GAT_STEP(v)                                                          \
  {                                                                          \
    const float xa0 = bflo((v).x), xa1 = bfhi((v).x);                        \
    const float xa2 = bflo((v).y), xa3 = bfhi((v).y);                        \
    const float xb0 = bflo((v).z), xb1 = bfhi((v).z);                        \
    const float xb2 = bflo((v).w), xb3 = bfhi((v).w);                        \
    const float e0 = xa0 + rxa0, e1 = xa1 + rxa1;                            \
    const float e2 = xa2 + rxa2, e3 = xa3 + rxa3;                            \
    const float f0 = xb0 + rxb0, f1 = xb1 + rxb1;                            \
    const float f2 = xb2 + rxb2, f3 = xb3 + rxb3;                            \
    float ps = e0 * ava.x;                                                   \
    ps = fmaf(e1, ava.y, ps); ps = fmaf(e2, ava.z, ps);                      \
    ps = fmaf(e3, ava.w, ps); ps = fmaf(f0, avb.x, ps);                      \
    ps = fmaf(f1, avb.y, ps); ps = fmaf(f2, avb.z, ps);                      \
    ps = fmaf(f3, avb.w, ps);                                                \
    float pa = fabsf(e0) * ava.x;                                            \
    pa = fmaf(fabsf(e1), ava.y, pa); pa = fmaf(fabsf(e2), ava.z, pa);        \
    pa = fmaf(fabsf(e3), ava.w, pa); pa = fmaf(fabsf(f0), avb.x, pa);        \
    pa = fmaf(fabsf(f1), avb.y, pa); pa = fmaf(fabsf(f2), avb.z, pa);        \
    pa = fmaf(fabsf(f3), avb.w, pa);                                         \
    float p = rowsum16(fmaf(0.6f, ps, 0.4f * pa));                           \
    const float w = __expf(p);                                               \
    l += w;                                                                  \
    a0 = fmaf(w, xa0, a0); a1 = fmaf(w, xa1, a1);                            \
    a2 = fmaf(w, xa2, a2); a3 = fmaf(w, xa3, a3);                            \
    b0 = fmaf(w, xb0, b0); b1 = fmaf(w, xb1, b1);                            \
    b2 = fmaf(w, xb2, b2); b3 = fmaf(w, xb3, b3);                            \
  }

  int i = row;
  for (; i + 3 < end; i += 4) {
    const u32 s0 = csr[i],     s1 = csr[i + 1];
    const u32 s2 = csr[i + 2], s3 = csr[i + 3];
    const uint4 v0 = *(const uint4*)(xbase + s0);
    const uint4 v1 = *(const uint4*)(xbase + s1);
    const uint4 v2 = *(const uint4*)(xbase + s2);
    const uint4 v3 = *(const uint4*)(xbase + s3);
    GAT_STEP(v0);
    GAT_STEP(v1);
    GAT_STEP(v2);
    GAT_STEP(v3);
  }
  for (; i < end; ++i) {
    const uint4 v0 = *(const uint4*)(xbase + csr[i]);
    GAT_STEP(v0);
  }
#undef GAT_STEP

  const float inv = 1.f / l;
  const float4 ba = *(const float4*)(bias + ch);
  const float4 bb = *(const float4*)(bias + ch + 4);
  uint4 ov;
  ov.x = (u32)f2bf(fmaf(a0, inv, ba.x)) | ((u32)f2bf(fmaf(a1, inv, ba.y)) << 16);
  ov.y = (u32)f2bf(fmaf(a2, inv, ba.z)) | ((u32)f2bf(fmaf(a3, inv, ba.w)) << 16);
  ov.z = (u32)f2bf(fmaf(b0, inv, bb.x)) | ((u32)f2bf(fmaf(b1, inv, bb.y)) << 16);
  ov.w = (u32)f2bf(fmaf(b2, inv, bb.z)) | ((u32)f2bf(fmaf(b3, inv, bb.w)) << 16);
  *(uint4*)(outb + (size_t)d * HC + ch) = ov;
}

// ---------------------------------------------------------------------------
// BatchNorm stats (bf16 input): stats[0..HC)=sum, [HC..2HC)=sumsq
// Grid 128 (R3 win): atomic contention depth == gridDim.
// ---------------------------------------------------------------------------
__global__ __launch_bounds__(256) void bn_stats(const u16* __restrict__ x,
                                                float* __restrict__ stats) {
  const int tid = threadIdx.x;
  const int rows_per = (N_NODES + gridDim.x - 1) / gridDim.x;
  const int r0 = blockIdx.x * rows_per;
  const int r1 = min(r0 + rows_per, N_NODES);
  const u32* xp = (const u32*)x;
  float s0 = 0.f, s1 = 0.f, q0 = 0.f, q1 = 0.f;
#pragma unroll 2
  for (int r = r0; r < r1; ++r) {
    const u32 v = xp[(size_t)r * 256 + tid];
    const float v0 = bflo(v), v1 = bfhi(v);
    s0 += v0; q0 += v0 * v0;
    s1 += v1; q1 += v1 * v1;
  }
  atomicAdd(&stats[2 * tid],          s0);
  atomicAdd(&stats[2 * tid + 1],      s1);
  atomicAdd(&stats[HC + 2 * tid],     q0);
  atomicAdd(&stats[HC + 2 * tid + 1], q1);
}

// ---------------------------------------------------------------------------
extern "C" void kernel_launch(void* const* d_in, const int* in_sizes, int n_in,
                              void* d_out, int out_size, void* d_ws, size_t ws_size,
                              hipStream_t stream) {
  const float* x_static = (const float*)d_in[0];
  const float* dyn      = (const float*)d_in[1];
  const int*   ei       = (const int*)d_in[2];
  const float* W_ih     = (const float*)d_in[3];
  const float* W_hh     = (const float*)d_in[4];
  const float* b_ih     = (const float*)d_in[5];
  const float* b_hh     = (const float*)d_in[6];
  const float* Wl1      = (const float*)d_in[7];
  const float* Wr1      = (const float*)d_in[8];
  const float* att1     = (const float*)d_in[9];
  const float* bg1      = (const float*)d_in[10];
  const float* Wl2      = (const float*)d_in[11];
  const float* Wr2      = (const float*)d_in[12];
  const float* att2     = (const float*)d_in[13];
  const float* bg2      = (const float*)d_in[14];
  const float* gamma1   = (const float*)d_in[15];
  const float* beta1    = (const float*)d_in[16];
  const float* gamma2   = (const float*)d_in[17];
  const float* beta2    = (const float*)d_in[18];
  const float* Wp       = (const float*)d_in[19];
  const float* bp       = (const float*)d_in[20];
  float* out = (float*)d_out;

  // ---- workspace carve (float units) ----
  float* ws = (float*)d_ws;
  size_t o = 0;
  float* c        = ws + o; o += (size_t)MP * HL;
  float* statsAll = ws + o; o += (size_t)T_SEQ * 4 * HC;
  float* bsum     = ws + o; o += 4 * HL;
  u16* packXHa = (u16*)(ws + o); o += (size_t)MP * KP1 / 2;
  u16* packXHb = (u16*)(ws + o); o += (size_t)MP * KP1 / 2;   // dbuf partner
  u16* packG1  = (u16*)(ws + o); o += (size_t)MP * KP1 / 2;
  u16* xlr     = (u16*)(ws + o); o += (size_t)MP * 1024 / 2;
  u16* gout    = (u16*)(ws + o); o += (size_t)MP * HC / 2;
  u16* wcat_bf = (u16*)(ws + o); o += (size_t)HC * KP1 / 2;
  u16* wlr1_bf = (u16*)(ws + o); o += (size_t)2 * HC * KP1 / 2;
  u16* wlr2_bf = (u16*)(ws + o); o += (size_t)2 * HC * HC / 2;
  u16* wp_bf   = (u16*)(ws + o); o += (size_t)EMB * HC / 2;
  int* deg      = (int*)(ws + o); o += N_NODES;
  int* cursor   = (int*)(ws + o); o += N_NODES;
  int* rowstart = (int*)(ws + o); o += N_NODES + 64;
  u32* csr      = (u32*)(ws + o); o += EP;

  // ---- per-launch init ----
  hipMemsetAsync(deg,      0, N_NODES * sizeof(int), stream);
  hipMemsetAsync(cursor,   0, N_NODES * sizeof(int), stream);
  hipMemsetAsync(statsAll, 0, (size_t)T_SEQ * 4 * HC * sizeof(float), stream);
  hipMemsetAsync(c,        0, (size_t)MP * HL * sizeof(float), stream);
  hipMemsetAsync(packXHa,  0, (size_t)MP * KP1 * sizeof(u16), stream);  // h=0 + pads
  hipMemsetAsync(packXHb,  0, (size_t)MP * KP1 * sizeof(u16), stream);
  hipMemsetAsync(packG1,   0, (size_t)MP * KP1 * sizeof(u16), stream);

  k_bias_sum<<<2, 256, 0, stream>>>(b_ih, b_hh, bsum);
  k_wcat_bf<<<(HC * KP1 + 255) / 256, 256, 0, stream>>>(W_ih, W_hh, wcat_bf);
  k_wlr1_bf<<<(2 * HC * KP1 + 255) / 256, 256, 0, stream>>>(Wl1, Wr1, wlr1_bf);
  k_wlr2_bf<<<(2 * HC * HC + 255) / 256, 256, 0, stream>>>(Wl2, Wr2, wlr2_bf);
  k_wp_bf<<<(EMB * HC + 255) / 256, 256, 0, stream>>>(Wp, wp_bf);
  k_pack_static<<<(N_NODES * DS + 255) / 256, 256, 0, stream>>>(x_static, packG1);
  k_pack_dyn<<<(N_NODES * DD + 255) / 256, 256, 0, stream>>>(dyn, packXHa);
  k_deg<<<(EP + 255) / 256, 256, 0, stream>>>(ei, deg);
  k_scan<<<1, 1024, 0, stream>>>(deg, rowstart);
  k_fill<<<(EP + 255) / 256, 256, 0, stream>>>(ei, rowstart, cursor, csr);

  const int GY = MP / 128;                       // 160 (divisible by 8)

  auto mk = [](const u16* A, int lda, const u16* W, int ldw, const float* bias,
               void* Cout, int ldc, int M, int Nc, int K, int cmode, int gxs,
               const float* dynp, float* cst, u16* pXH, u16* pG1, int t_next,
               const float* bnst, const float* bng, const float* bnb, int abn) {
    GemmArgs g;
    g.A = A; g.lda = lda; g.W = W; g.ldw = ldw; g.bias = bias;
    g.Cout = Cout; g.ldc = ldc; g.M = M; g.Nc = Nc; g.K = K;
    g.cmode = cmode; g.gxs = gxs; g.dynp = dynp; g.cst = cst;
    g.pXH = pXH; g.pG1 = pG1; g.t_next = t_next;
    g.bnst = bnst; g.bng = bng; g.bnb = bnb; g.abn = abn;
    return g;
  };

  auto lstmArgs = [&](int t) {
    u16* xhr = (t & 1) ? packXHb : packXHa;      // read buffer (x_t, h_t)
    u16* xhw = (t & 1) ? packXHa : packXHb;      // write buffer (x_{t+1}, h_{t+1})
    return mk(xhr, KP1, wcat_bf, KP1, bsum, nullptr, 0, MP, HC, KP1, 2, 2,
              dyn, c, xhw, packG1, t + 1, nullptr, nullptr, nullptr, 0);
  };

  // ---- LSTM step 0 ----
  gemm_mfma<<<4 * GY, 256, 0, stream>>>(lstmArgs(0));

  for (int t = 0; t < T_SEQ; ++t) {
    float* stats = statsAll + (size_t)t * 4 * HC;

    // ---- GAT layer 1: GEMM -> edge softmax -> stats ----
    gemm_mfma<<<8 * GY, 256, 0, stream>>>(
        mk(packG1, KP1, wlr1_bf, KP1, nullptr, xlr, 1024, MP, 2 * HC, KP1, 1, 3,
           nullptr, nullptr, nullptr, nullptr, 0, nullptr, nullptr, nullptr, 0));
    gat_edge<<<N_NODES / 4, 256, 0, stream>>>(xlr, att1, bg1, rowstart, csr, gout);
    bn_stats<<<128, 256, 0, stream>>>(gout, stats);

    // ---- GAT layer 2: GEMM with fused BN1+ReLU on A (A = raw gout) ----
    gemm_bn<<<8 * GY, 256, 0, stream>>>(
        mk(gout, HC, wlr2_bf, HC, nullptr, xlr, 1024, MP, 2 * HC, HC, 1, 3,
           nullptr, nullptr, nullptr, nullptr, 0, stats, gamma1, beta1, 1));
    gat_edge<<<N_NODES / 4, 256, 0, stream>>>(xlr, att2, bg2, rowstart, csr, gout);
    bn_stats<<<128, 256, 0, stream>>>(gout, stats + 2 * HC);

    // ---- proj (t, fused BN2+ReLU on A) merged with LSTM GEMM (t+1) ----
    GemmArgs proj = mk(gout, HC, wp_bf, HC, bp, out + t * EMB, T_SEQ * EMB,
                       N_NODES, EMB, HC, 0, 0,
                       nullptr, nullptr, nullptr, nullptr, 0,
                       stats + 2 * HC, gamma2, beta2, 1);
    if (t + 1 < T_SEQ) {
      gemm_dual<<<5 * GY, 256, 0, stream>>>(lstmArgs(t + 1), proj, 4 * GY);
    } else {
      gemm_bn<<<1 * GY, 256, 0, stream>>>(proj);
    }
  }
}

// Round 11
// 2185.467 us; speedup vs baseline: 1.0930x; 1.0167x over previous
//
#include <hip/hip_runtime.h>
#include <math.h>

typedef unsigned short u16;
typedef unsigned int u32;

#define N_NODES 20000
#define MP      20480            // N padded to multiple of 1024 (128 x 8 XCD groups)
#define T_SEQ   8
#define DS      16
#define DD      8
#define E_EDGES 320000
#define HL      128
#define GH      4
#define GC      128
#define HC      512
#define EMB     64
#define KP1     160              // padded K for LSTM (136) and GAT1 (144)
#define EP      (E_EDGES + N_NODES)

typedef __attribute__((ext_vector_type(8))) short bf16x8;
typedef __attribute__((ext_vector_type(4))) float f32x4;
typedef __attribute__((ext_vector_type(2))) float f32x2;

__device__ __forceinline__ u16 f2bf(float f) {
  u32 u = __float_as_uint(f);
  u += 0x7fff + ((u >> 16) & 1);   // RNE (inputs are finite)
  return (u16)(u >> 16);
}
__device__ __forceinline__ float bflo(u32 v) { return __uint_as_float(v << 16); }
__device__ __forceinline__ float bfhi(u32 v) { return __uint_as_float(v & 0xffff0000u); }
__device__ __forceinline__ float bf16f(u16 v) { return __uint_as_float((u32)v << 16); }

__device__ __forceinline__ void gld16(const void* g, void* l) {
  __builtin_amdgcn_global_load_lds(
      (const __attribute__((address_space(1))) void*)g,
      (__attribute__((address_space(3))) void*)l, 16, 0, 0);
}

// sum across each 16-lane row via DPP row_ror (pure VALU, no LDS pipe)
__device__ __forceinline__ float rowsum16(float p) {
  p += __int_as_float(__builtin_amdgcn_update_dpp(0, __float_as_int(p), 0x121, 0xf, 0xf, false));
  p += __int_as_float(__builtin_amdgcn_update_dpp(0, __float_as_int(p), 0x122, 0xf, 0xf, false));
  p += __int_as_float(__builtin_amdgcn_update_dpp(0, __float_as_int(p), 0x124, 0xf, 0xf, false));
  p += __int_as_float(__builtin_amdgcn_update_dpp(0, __float_as_int(p), 0x128, 0xf, 0xf, false));
  return p;
}

// R11: packed BN+ReLU+pack on a bf16 pair: v_pk_fma + v_pk_max +
// v_cvt_pk_bf16_f32 (RNE, == f2bf bitwise for finite post-ReLU values).
// ~5 VALU/pair vs bn2c's ~13. Pad-row NaNs are only ever written to
// xlr/C pad rows that nothing reads (csr sources & bn_stats rows < N).
__device__ __forceinline__ u32 bn2p(u32 xw, f32x2 s, f32x2 o) {
  f32x2 x = {__uint_as_float(xw << 16), __uint_as_float(xw & 0xffff0000u)};
  f32x2 z = __builtin_elementwise_fma(x, s, o);
  z = __builtin_elementwise_max(z, (f32x2){0.f, 0.f});
  u32 r;
  asm("v_cvt_pk_bf16_f32 %0, %1, %2" : "=v"(r) : "v"(z.x), "v"(z.y));
  return r;
}

// ---------------------------------------------------------------------------
// bf16 MFMA GEMM: C[M,Nc] = A[M,K] @ W[Nc,K]^T (+bias).
// 128x128 tile, BK=32, double-buffered LDS (prefetch-after-barrier).
// XCD-aware swizzle (id%8 -> XCD); bf16 out via LDS-staged coalesced epilogue.
// cmode: 0 = f32 out, 1 = bf16 out, 2 = fused LSTM pointwise epilogue.
// abn=1 (gemm_bn / dual-proj only): BatchNorm+ReLU fused into A-staging.
// R10: per-channel (s,o) coefs computed ONCE per block into LDS.
// R11: BN transform in packed math (pk_fma/pk_max/cvt_pk_bf16).
// ---------------------------------------------------------------------------
struct GemmArgs {
  const u16* A; const u16* W; const float* bias; void* Cout;
  const float* dynp; float* cst; u16* pXH; u16* pG1;
  const float* bnst; const float* bng; const float* bnb;   // stats, gamma, beta
  int lda, ldw, ldc, M, Nc, K, cmode, gxs, t_next, abn;
};

__device__ __forceinline__ void gemm_body(u32 id, const GemmArgs& g, u16* smem,
                                          float* cs, float* co) {
  const u16* __restrict__ A    = g.A;
  const u16* __restrict__ W    = g.W;
  const float* __restrict__ bias = g.bias;
  const int lda = g.lda, ldw = g.ldw, ldc = g.ldc;
  const int M = g.M, Nc = g.Nc, K = g.K, cmode = g.cmode;
  const int abn = g.abn;

  u16* Asm = smem;
  u16* Bsm = smem + 8192;

  const int tid = threadIdx.x;
  const int wave = tid >> 6, lane = tid & 63;
  const int wm = (wave >> 1) << 6, wn = (wave & 1) << 6;

  const int xcd = id & 7;
  const u32 sl = id >> 3;
  const int GXm = (1 << g.gxs) - 1;
  const int bn = (int)(sl & GXm) << 7;
  const int bm = (xcd + (int)((sl >> g.gxs) << 3)) << 7;

  // ---- one-time BN coef build (abn kernels only; K==HC==512 there) ----
  if (abn) {
    const int c0 = tid * 2, c1 = c0 + 1;
    const float inv_n = 1.f / N_NODES;
    const float m0 = g.bnst[c0] * inv_n, m1 = g.bnst[c1] * inv_n;
    const float i0 = rsqrtf(g.bnst[HC + c0] * inv_n - m0 * m0 + 1e-5f);
    const float i1 = rsqrtf(g.bnst[HC + c1] * inv_n - m1 * m1 + 1e-5f);
    const float s0 = i0 * g.bng[c0], s1 = i1 * g.bng[c1];
    cs[c0] = s0; cs[c1] = s1;
    co[c0] = fmaf(-m0, s0, g.bnb[c0]);
    co[c1] = fmaf(-m1, s1, g.bnb[c1]);
    __syncthreads();
  }

  f32x4 acc[4][4];
#pragma unroll
  for (int i = 0; i < 4; ++i)
#pragma unroll
    for (int j = 0; j < 4; ++j) acc[i][j] = (f32x4){0.f, 0.f, 0.f, 0.f};

  const int qr = lane >> 2;
  const int qc = (lane & 3) << 3;
  const int q0 = wave * 2, q1 = wave * 2 + 1;
  const int ra0 = bm + q0 * 16 + qr;
  const int ra1 = bm + q1 * 16 + qr;
  int rb0 = bn + q0 * 16 + qr; if (rb0 >= Nc) rb0 = Nc - 1;
  int rb1 = bn + q1 * 16 + qr; if (rb1 >= Nc) rb1 = Nc - 1;

  const u16* pa0 = A + (size_t)ra0 * lda + qc;
  const u16* pa1 = A + (size_t)ra1 * lda + qc;
  const u16* pb0 = W + (size_t)rb0 * ldw + qc;
  const u16* pb1 = W + (size_t)rb1 * ldw + qc;

  const int fm = lane & 15;
  const int fk = (lane >> 4) << 3;

#define BN_STAGE(xr0, xr1, col, dofs)                                         \
  {                                                                           \
    const float4 sA = *(const float4*)&cs[(col)];                             \
    const float4 sB = *(const float4*)&cs[(col) + 4];                         \
    const float4 oA = *(const float4*)&co[(col)];                             \
    const float4 oB = *(const float4*)&co[(col) + 4];                         \
    uint4 w0, w1;                                                             \
    w0.x = bn2p((xr0).x, (f32x2){sA.x, sA.y}, (f32x2){oA.x, oA.y});           \
    w0.y = bn2p((xr0).y, (f32x2){sA.z, sA.w}, (f32x2){oA.z, oA.w});           \
    w0.z = bn2p((xr0).z, (f32x2){sB.x, sB.y}, (f32x2){oB.x, oB.y});           \
    w0.w = bn2p((xr0).w, (f32x2){sB.z, sB.w}, (f32x2){oB.z, oB.w});           \
    w1.x = bn2p((xr1).x, (f32x2){sA.x, sA.y}, (f32x2){oA.x, oA.y});           \
    w1.y = bn2p((xr1).y, (f32x2){sA.z, sA.w}, (f32x2){oA.z, oA.w});           \
    w1.z = bn2p((xr1).z, (f32x2){sB.x, sB.y}, (f32x2){oB.x, oB.y});           \
    w1.w = bn2p((xr1).w, (f32x2){sB.z, sB.w}, (f32x2){oB.z, oB.w});           \
    *(uint4*)&Asm[(dofs) + q0 * 512 + lane * 8] = w0;                         \
    *(uint4*)&Asm[(dofs) + q1 * 512 + lane * 8] = w1;                         \
  }

  // ---- prologue: stage iter 0 ----
  if (abn) {
    const uint4 x0 = *(const uint4*)pa0;
    const uint4 x1 = *(const uint4*)pa1;
    BN_STAGE(x0, x1, qc, 0);
  } else {
    gld16(pa0, &Asm[q0 * 512]);
    gld16(pa1, &Asm[q1 * 512]);
  }
  gld16(pb0, &Bsm[q0 * 512]);
  gld16(pb1, &Bsm[q1 * 512]);
  pa0 += 32; pa1 += 32; pb0 += 32; pb1 += 32;

  const int iters = K >> 5;
#pragma unroll 2
  for (int it = 0; it < iters; ++it) {
    const int cur = (it & 1) * 4096;
    uint4 xr0, xr1;
    if (abn && it + 1 < iters) {       // issue before barrier: latency hidden
      xr0 = *(const uint4*)pa0;
      xr1 = *(const uint4*)pa1;
    }
    __syncthreads();
    if (it + 1 < iters) {
      const int nxt = cur ^ 4096;
      if (abn) {
        const int ncol = (it + 1) * 32 + qc;
        BN_STAGE(xr0, xr1, ncol, nxt);
      } else {
        gld16(pa0, &Asm[nxt + q0 * 512]);
        gld16(pa1, &Asm[nxt + q1 * 512]);
      }
      pa0 += 32; pa1 += 32;
      gld16(pb0, &Bsm[nxt + q0 * 512]);
      gld16(pb1, &Bsm[nxt + q1 * 512]);
      pb0 += 32; pb1 += 32;
    }
    bf16x8 af[4], bfr[4];
#pragma unroll
    for (int i = 0; i < 4; ++i)
      af[i] = *(const bf16x8*)&Asm[cur + (wm + i * 16 + fm) * 32 + fk];
#pragma unroll
    for (int j = 0; j < 4; ++j)
      bfr[j] = *(const bf16x8*)&Bsm[cur + (wn + j * 16 + fm) * 32 + fk];
#pragma unroll
    for (int i = 0; i < 4; ++i)
#pragma unroll
      for (int j = 0; j < 4; ++j)
        acc[i][j] = __builtin_amdgcn_mfma_f32_16x16x32_bf16(af[i], bfr[j], acc[i][j], 0, 0, 0);
  }
#undef BN_STAGE

  const int cn = lane & 15, cm = (lane >> 4) << 2;
  if (cmode >= 1) {
    // stage bf16 C tile (with bias) into LDS, coalesced layout
    __syncthreads();
#pragma unroll
    for (int j = 0; j < 4; ++j) {
      const int c = wn + j * 16 + cn;
      const float bb = bias ? bias[bn + c] : 0.f;
#pragma unroll
      for (int i = 0; i < 4; ++i) {
#pragma unroll
        for (int r = 0; r < 4; ++r)
          smem[(wm + i * 16 + cm + r) * 128 + c] = f2bf(acc[i][j][r] + bb);
      }
    }
    __syncthreads();
    if (cmode == 1) {
      u16* outc = (u16*)g.Cout;
#pragma unroll
      for (int k = 0; k < 8; ++k) {
        const int idx = tid + k * 256;
        const int r = idx >> 4, cc = (idx & 15) << 3;
        *(uint4*)(outc + (size_t)(bm + r) * ldc + bn + cc) = *(const uint4*)&smem[r * 128 + cc];
      }
    } else {
      // ---- fused LSTM pointwise (cmode == 2) ----
      float* __restrict__ cst = g.cst;
      u16* __restrict__ pXH = g.pXH;
      u16* __restrict__ pG1 = g.pG1;
      const float* __restrict__ dynp = g.dynp;
      const int jbase = bn >> 2;
#pragma unroll 4
      for (int k = 0; k < 16; ++k) {
        const int idx = tid + k * 256;           // 128 rows x 32 j's
        const int r = idx >> 5, jl = idx & 31;
        const int n = bm + r;
        const int jg = jbase + jl;
        const u32* sp = (const u32*)&smem[r * 128 + jl * 4];
        const u32 w0 = sp[0], w1 = sp[1];
        const float gi = bflo(w0), gf = bfhi(w0);
        const float gg = bflo(w1), go = bfhi(w1);
        const float si = 1.f / (1.f + __expf(-gi));
        const float sf = 1.f / (1.f + __expf(-gf));
        const float so = 1.f / (1.f + __expf(-go));
        const size_t ci = (size_t)n * HL + jg;
        const float cnv = sf * cst[ci] + si * tanhf(gg);
        cst[ci] = cnv;
        const u16 hb = f2bf(so * tanhf(cnv));
        pXH[(size_t)n * KP1 + DD + jg] = hb;
        pG1[(size_t)n * KP1 + DS + jg] = hb;
        if (jl < DD && bn == 0 && g.t_next < T_SEQ && n < N_NODES)
          pXH[(size_t)n * KP1 + jl] =
              f2bf(dynp[(size_t)n * (T_SEQ * DD) + g.t_next * DD + jl]);
      }
    }
  } else {
#pragma unroll
    for (int j = 0; j < 4; ++j) {
      const int c = bn + wn + j * 16 + cn;
      if (c >= Nc) continue;
      const float bb = bias ? bias[c] : 0.f;
#pragma unroll
      for (int i = 0; i < 4; ++i) {
#pragma unroll
        for (int r = 0; r < 4; ++r) {
          const int m = bm + wm + i * 16 + cm + r;
          if (m >= M) continue;
          ((float*)g.Cout)[(size_t)m * ldc + c] = acc[i][j][r] + bb;
        }
      }
    }
  }
}

// 32KB-LDS variant (no BN) — keeps 5 blocks/CU for GAT1/LSTM GEMMs.
__global__ __launch_bounds__(256) void gemm_mfma(GemmArgs g) {
  __shared__ u16 smem[16384];
  gemm_body(blockIdx.x, g, smem, nullptr, nullptr);
}

// 36KB-LDS variant with per-block BN coef cache (GAT2 / final proj).
__global__ __launch_bounds__(256) void gemm_bn(GemmArgs g) {
  __shared__ u16 smem[16384];
  __shared__ float cs[HC], co[HC];
  gemm_body(blockIdx.x, g, smem, cs, co);
}

// merged dispatch: blocks [0,n0) run g0 (LSTM t+1, abn=0), rest g1 (proj t,
// abn=1). ~3 blocks/CU resident -> the extra 4KB LDS never binds here.
__global__ __launch_bounds__(256) void gemm_dual(GemmArgs g0, GemmArgs g1, int n0) {
  __shared__ u16 smem[16384];
  __shared__ float cs[HC], co[HC];
  if ((int)blockIdx.x < n0) gemm_body(blockIdx.x, g0, smem, cs, co);
  else                      gemm_body(blockIdx.x - n0, g1, smem, cs, co);
}

// ---------------------------------------------------------------------------
// Setup / conversion kernels (once per launch; tiny)
// ---------------------------------------------------------------------------
// Gate-interleaved bias: col = j*4 + gate
__global__ void k_bias_sum(const float* __restrict__ b_ih,
                           const float* __restrict__ b_hh,
                           float* __restrict__ bsum) {
  int i = blockIdx.x * blockDim.x + threadIdx.x;
  if (i >= 4 * HL) return;
  int g = i & 3, j = i >> 2;
  bsum[i] = b_ih[g * HL + j] + b_hh[g * HL + j];
}

// Gate-interleaved fused LSTM weight: out row jj -> gate jj&3, unit jj>>2
__global__ void k_wcat_bf(const float* __restrict__ W_ih,
                          const float* __restrict__ W_hh,
                          u16* __restrict__ w) {
  int idx = blockIdx.x * blockDim.x + threadIdx.x;
  if (idx >= HC * KP1) return;
  int jj = idx / KP1, k = idx - jj * KP1;
  int srow = (jj & 3) * HL + (jj >> 2);
  float v = 0.f;
  if (k < DD) v = W_ih[srow * DD + k];
  else if (k < DD + HL) v = W_hh[srow * HL + (k - DD)];
  w[idx] = f2bf(v);
}

__global__ void k_wlr1_bf(const float* __restrict__ Wl,
                          const float* __restrict__ Wr,
                          u16* __restrict__ w) {
  int idx = blockIdx.x * blockDim.x + threadIdx.x;
  if (idx >= 2 * HC * KP1) return;
  int j = idx / KP1, k = idx - j * KP1;
  const float* src = (j < HC) ? Wl : Wr;
  int jj = j & (HC - 1);
  float v = (k < DS + HL) ? src[jj * (DS + HL) + k] : 0.f;
  w[idx] = f2bf(v);
}

__global__ void k_wlr2_bf(const float* __restrict__ Wl,
                          const float* __restrict__ Wr,
                          u16* __restrict__ w) {
  int idx = blockIdx.x * blockDim.x + threadIdx.x;
  if (idx >= 2 * HC * HC) return;
  int j = idx >> 9, k = idx & (HC - 1);
  const float* src = (j < HC) ? Wl : Wr;
  int jj = j & (HC - 1);
  w[idx] = f2bf(src[jj * HC + k]);
}

__global__ void k_wp_bf(const float* __restrict__ Wp, u16* __restrict__ w) {
  int idx = blockIdx.x * blockDim.x + threadIdx.x;
  if (idx < EMB * HC) w[idx] = f2bf(Wp[idx]);
}

__global__ void k_pack_static(const float* __restrict__ xs, u16* __restrict__ packG1) {
  int idx = blockIdx.x * blockDim.x + threadIdx.x;
  if (idx >= N_NODES * DS) return;
  int n = idx >> 4, k = idx & 15;
  packG1[(size_t)n * KP1 + k] = f2bf(xs[idx]);
}

__global__ void k_pack_dyn(const float* __restrict__ dyn, u16* __restrict__ packXH) {
  int idx = blockIdx.x * blockDim.x + threadIdx.x;
  if (idx >= N_NODES * DD) return;
  int n = idx >> 3, k = idx & 7;
  packXH[(size_t)n * KP1 + k] = f2bf(dyn[(size_t)n * (T_SEQ * DD) + k]);
}

// ---------------------------------------------------------------------------
// CSR build (dst-sorted), rebuilt every launch. Entries pre-shifted (s<<11).
// ---------------------------------------------------------------------------
__global__ void k_deg(const int* __restrict__ ei, int* __restrict__ deg) {
  int e = blockIdx.x * blockDim.x + threadIdx.x;
  if (e >= EP) return;
  int d = (e < E_EDGES) ? ei[E_EDGES + e] : (e - E_EDGES);
  atomicAdd(&deg[d], 1);
}

__global__ __launch_bounds__(1024) void k_scan(const int* __restrict__ deg,
                                               int* __restrict__ rowstart) {
  __shared__ int buf[1024];
  __shared__ int carry_s;
  const int tid = threadIdx.x;
  if (tid == 0) carry_s = 0;
  __syncthreads();
  for (int base = 0; base < N_NODES; base += 1024) {
    int v = (base + tid < N_NODES) ? deg[base + tid] : 0;
    buf[tid] = v;
    __syncthreads();
    for (int off = 1; off < 1024; off <<= 1) {
      int add = (tid >= off) ? buf[tid - off] : 0;
      __syncthreads();
      buf[tid] += add;
      __syncthreads();
    }
    int incl = buf[tid];
    int carry = carry_s;
    if (base + tid < N_NODES) rowstart[base + tid] = carry + incl - v;
    __syncthreads();
    if (tid == 1023) carry_s = carry + incl;
    __syncthreads();
  }
  if (tid == 0) rowstart[N_NODES] = carry_s;
}

__global__ void k_fill(const int* __restrict__ ei,
                       const int* __restrict__ rowstart,
                       int* __restrict__ cursor, u32* __restrict__ csr) {
  int e = blockIdx.x * blockDim.x + threadIdx.x;
  if (e >= EP) return;
  int s, d;
  if (e < E_EDGES) { s = ei[e]; d = ei[E_EDGES + e]; }
  else             { s = d = e - E_EDGES; }
  int pos = atomicAdd(&cursor[d], 1);
  csr[rowstart[d] + pos] = (u32)s << 11;
}

// ---------------------------------------------------------------------------
// GATv2 edge softmax + aggregation (proven R0 loop, pre-shifted csr).
// FLOOR at ~50us: R1 ILP-pipeline (+8%), R4 degree-sort (null), R6
// head-split (null: NOT L2-capacity-bound), R7 packed-f32 (occupancy
// 45->30%, +4%) all REVERTED. Mixed VALU/latency regime; leave alone.
// ---------------------------------------------------------------------------
__global__ __launch_bounds__(256) void gat_edge(
    const u16* __restrict__ xlr,
    const float* __restrict__ att, const float* __restrict__ bias,
    const int* __restrict__ rowstart, const u32* __restrict__ csr,
    u16* __restrict__ outb)
{
  const int wave = threadIdx.x >> 6, lane = threadIdx.x & 63;
  const int d = blockIdx.x * 4 + wave;
  const int ch = lane * 8;                  // [0,512); head = lane>>4
  const uint4 vr = *(const uint4*)(xlr + (size_t)d * 1024 + 512 + ch);
  const float rxa0 = bflo(vr.x), rxa1 = bfhi(vr.x), rxa2 = bflo(vr.y), rxa3 = bfhi(vr.y);
  const float rxb0 = bflo(vr.z), rxb1 = bfhi(vr.z), rxb2 = bflo(vr.w), rxb3 = bfhi(vr.w);
  const float4 ava = *(const float4*)(att + ch);
  const float4 avb = *(const float4*)(att + ch + 4);
  const int row = rowstart[d], end = rowstart[d + 1];
  const char* __restrict__ xbase = (const char*)(xlr + ch);  // + (s<<11) bytes

  float l = 0.f;
  float a0 = 0.f, a1 = 0.f, a2 = 0.f, a3 = 0.f;
  float b0 = 0.f, b1 = 0.f, b2 = 0.f, b3 = 0.f;

#define GAT_STEP(v)                                                          \
  {                                                                          \
    const float xa0 = bflo((v).x), xa1 = bfhi((v).x);                        \
    const float xa2 = bflo((v).y), xa3 = bfhi((v).y);                        \
    const float xb0 = bflo((v).z), xb1 = bfhi((v).z);                        \
    const float xb2 = bflo((v).w), xb3 = bfhi((v).w);                        \
    const float e0 = xa0 + rxa0, e1 = xa1 + rxa1;                            \
    const float e2 = xa2 + rxa2, e3 = xa3 + rxa3;                            \
    const float f0 = xb0 + rxb0, f1 = xb1 + rxb1;                            \
    const float f2 = xb2 + rxb2, f3 = xb3 + rxb3;                            \
    float ps = e0 * ava.x;                                                   \
    ps = fmaf(e1, ava.y, ps); ps = fmaf(e2, ava.z, ps);                      \
    ps = fmaf(e3, ava.w, ps); ps = fmaf(f0, avb.x, ps);                      \
    ps = fmaf(f1, avb.y, ps); ps = fmaf(f2, avb.z, ps);                      \
    ps = fmaf(f3, avb.w, ps);                                                \
    float pa = fabsf(e0) * ava.x;                                            \
    pa = fmaf(fabsf(e1), ava.y, pa); pa = fmaf(fabsf(e2), ava.z, pa);        \
    pa = fmaf(fabsf(e3), ava.w, pa); pa = fmaf(fabsf(f0), avb.x, pa);        \
    pa = fmaf(fabsf(f1), avb.y, pa); pa = fmaf(fabsf(f2), avb.z, pa);        \
    pa = fmaf(fabsf(f3), avb.w, pa);                                         \
    float p = rowsum16(fmaf(0.6f, ps, 0.4f * pa));                           \
    const float w = __expf(p);                                               \
    l += w;                                                                  \
    a0 = fmaf(w, xa0, a0); a1 = fmaf(w, xa1, a1);                            \
    a2 = fmaf(w, xa2, a2); a3 = fmaf(w, xa3, a3);                            \
    b0 = fmaf(w, xb0, b0); b1 = fmaf(w, xb1, b1);                            \
    b2 = fmaf(w, xb2, b2); b3 = fmaf(w, xb3, b3);                            \
  }

  int i = row;
  for (; i + 3 < end; i += 4) {
    const u32 s0 = csr[i],     s1 = csr[i + 1];
    const u32 s2 = csr[i + 2], s3 = csr[i + 3];
    const uint4 v0 = *(const uint4*)(xbase + s0);
    const uint4 v1 = *(const uint4*)(xbase + s1);
    const uint4 v2 = *(const uint4*)(xbase + s2);
    const uint4 v3 = *(const uint4*)(xbase + s3);
    GAT_STEP(v0);
    GAT_STEP(v1);
    GAT_STEP(v2);
    GAT_STEP(v3);
  }
  for (; i < end; ++i) {
    const uint4 v0 = *(const uint4*)(xbase + csr[i]);
    GAT_STEP(v0);
  }
#undef GAT_STEP

  const float inv = 1.f / l;
  const float4 ba = *(const float4*)(bias + ch);
  const float4 bb = *(const float4*)(bias + ch + 4);
  uint4 ov;
  ov.x = (u32)f2bf(fmaf(a0, inv, ba.x)) | ((u32)f2bf(fmaf(a1, inv, ba.y)) << 16);
  ov.y = (u32)f2bf(fmaf(a2, inv, ba.z)) | ((u32)f2bf(fmaf(a3, inv, ba.w)) << 16);
  ov.z = (u32)f2bf(fmaf(b0, inv, bb.x)) | ((u32)f2bf(fmaf(b1, inv, bb.y)) << 16);
  ov.w = (u32)f2bf(fmaf(b2, inv, bb.z)) | ((u32)f2bf(fmaf(b3, inv, bb.w)) << 16);
  *(uint4*)(outb + (size_t)d * HC + ch) = ov;
}

// ---------------------------------------------------------------------------
// BatchNorm stats (bf16 input): stats[0..HC)=sum, [HC..2HC)=sumsq
// Grid 128 (R3 win): atomic contention depth == gridDim.
// ---------------------------------------------------------------------------
__global__ __launch_bounds__(256) void bn_stats(const u16* __restrict__ x,
                                                float* __restrict__ stats) {
  const int tid = threadIdx.x;
  const int rows_per = (N_NODES + gridDim.x - 1) / gridDim.x;
  const int r0 = blockIdx.x * rows_per;
  const int r1 = min(r0 + rows_per, N_NODES);
  const u32* xp = (const u32*)x;
  float s0 = 0.f, s1 = 0.f, q0 = 0.f, q1 = 0.f;
#pragma unroll 2
  for (int r = r0; r < r1; ++r) {
    const u32 v = xp[(size_t)r * 256 + tid];
    const float v0 = bflo(v), v1 = bfhi(v);
    s0 += v0; q0 += v0 * v0;
    s1 += v1; q1 += v1 * v1;
  }
  atomicAdd(&stats[2 * tid],          s0);
  atomicAdd(&stats[2 * tid + 1],      s1);
  atomicAdd(&stats[HC + 2 * tid],     q0);
  atomicAdd(&stats[HC + 2 * tid + 1], q1);
}

// ---------------------------------------------------------------------------
extern "C" void kernel_launch(void* const* d_in, const int* in_sizes, int n_in,
                              void* d_out, int out_size, void* d_ws, size_t ws_size,
                              hipStream_t stream) {
  const float* x_static = (const float*)d_in[0];
  const float* dyn      = (const float*)d_in[1];
  const int*   ei       = (const int*)d_in[2];
  const float* W_ih     = (const float*)d_in[3];
  const float* W_hh     = (const float*)d_in[4];
  const float* b_ih     = (const float*)d_in[5];
  const float* b_hh     = (const float*)d_in[6];
  const float* Wl1      = (const float*)d_in[7];
  const float* Wr1      = (const float*)d_in[8];
  const float* att1     = (const float*)d_in[9];
  const float* bg1      = (const float*)d_in[10];
  const float* Wl2      = (const float*)d_in[11];
  const float* Wr2      = (const float*)d_in[12];
  const float* att2     = (const float*)d_in[13];
  const float* bg2      = (const float*)d_in[14];
  const float* gamma1   = (const float*)d_in[15];
  const float* beta1    = (const float*)d_in[16];
  const float* gamma2   = (const float*)d_in[17];
  const float* beta2    = (const float*)d_in[18];
  const float* Wp       = (const float*)d_in[19];
  const float* bp       = (const float*)d_in[20];
  float* out = (float*)d_out;

  // ---- workspace carve (float units) ----
  float* ws = (float*)d_ws;
  size_t o = 0;
  float* c        = ws + o; o += (size_t)MP * HL;
  float* statsAll = ws + o; o += (size_t)T_SEQ * 4 * HC;
  float* bsum     = ws + o; o += 4 * HL;
  u16* packXHa = (u16*)(ws + o); o += (size_t)MP * KP1 / 2;
  u16* packXHb = (u16*)(ws + o); o += (size_t)MP * KP1 / 2;   // dbuf partner
  u16* packG1  = (u16*)(ws + o); o += (size_t)MP * KP1 / 2;
  u16* xlr     = (u16*)(ws + o); o += (size_t)MP * 1024 / 2;
  u16* gout    = (u16*)(ws + o); o += (size_t)MP * HC / 2;
  u16* wcat_bf = (u16*)(ws + o); o += (size_t)HC * KP1 / 2;
  u16* wlr1_bf = (u16*)(ws + o); o += (size_t)2 * HC * KP1 / 2;
  u16* wlr2_bf = (u16*)(ws + o); o += (size_t)2 * HC * HC / 2;
  u16* wp_bf   = (u16*)(ws + o); o += (size_t)EMB * HC / 2;
  int* deg      = (int*)(ws + o); o += N_NODES;
  int* cursor   = (int*)(ws + o); o += N_NODES;
  int* rowstart = (int*)(ws + o); o += N_NODES + 64;
  u32* csr      = (u32*)(ws + o); o += EP;

  // ---- per-launch init ----
  hipMemsetAsync(deg,      0, N_NODES * sizeof(int), stream);
  hipMemsetAsync(cursor,   0, N_NODES * sizeof(int), stream);
  hipMemsetAsync(statsAll, 0, (size_t)T_SEQ * 4 * HC * sizeof(float), stream);
  hipMemsetAsync(c,        0, (size_t)MP * HL * sizeof(float), stream);
  hipMemsetAsync(packXHa,  0, (size_t)MP * KP1 * sizeof(u16), stream);  // h=0 + pads
  hipMemsetAsync(packXHb,  0, (size_t)MP * KP1 * sizeof(u16), stream);
  hipMemsetAsync(packG1,   0, (size_t)MP * KP1 * sizeof(u16), stream);

  k_bias_sum<<<2, 256, 0, stream>>>(b_ih, b_hh, bsum);
  k_wcat_bf<<<(HC * KP1 + 255) / 256, 256, 0, stream>>>(W_ih, W_hh, wcat_bf);
  k_wlr1_bf<<<(2 * HC * KP1 + 255) / 256, 256, 0, stream>>>(Wl1, Wr1, wlr1_bf);
  k_wlr2_bf<<<(2 * HC * HC + 255) / 256, 256, 0, stream>>>(Wl2, Wr2, wlr2_bf);
  k_wp_bf<<<(EMB * HC + 255) / 256, 256, 0, stream>>>(Wp, wp_bf);
  k_pack_static<<<(N_NODES * DS + 255) / 256, 256, 0, stream>>>(x_static, packG1);
  k_pack_dyn<<<(N_NODES * DD + 255) / 256, 256, 0, stream>>>(dyn, packXHa);
  k_deg<<<(EP + 255) / 256, 256, 0, stream>>>(ei, deg);
  k_scan<<<1, 1024, 0, stream>>>(deg, rowstart);
  k_fill<<<(EP + 255) / 256, 256, 0, stream>>>(ei, rowstart, cursor, csr);

  const int GY = MP / 128;                       // 160 (divisible by 8)

  auto mk = [](const u16* A, int lda, const u16* W, int ldw, const float* bias,
               void* Cout, int ldc, int M, int Nc, int K, int cmode, int gxs,
               const float* dynp, float* cst, u16* pXH, u16* pG1, int t_next,
               const float* bnst, const float* bng, const float* bnb, int abn) {
    GemmArgs g;
    g.A = A; g.lda = lda; g.W = W; g.ldw = ldw; g.bias = bias;
    g.Cout = Cout; g.ldc = ldc; g.M = M; g.Nc = Nc; g.K = K;
    g.cmode = cmode; g.gxs = gxs; g.dynp = dynp; g.cst = cst;
    g.pXH = pXH; g.pG1 = pG1; g.t_next = t_next;
    g.bnst = bnst; g.bng = bng; g.bnb = bnb; g.abn = abn;
    return g;
  };

  auto lstmArgs = [&](int t) {
    u16* xhr = (t & 1) ? packXHb : packXHa;      // read buffer (x_t, h_t)
    u16* xhw = (t & 1) ? packXHa : packXHb;      // write buffer (x_{t+1}, h_{t+1})
    return mk(xhr, KP1, wcat_bf, KP1, bsum, nullptr, 0, MP, HC, KP1, 2, 2,
              dyn, c, xhw, packG1, t + 1, nullptr, nullptr, nullptr, 0);
  };

  // ---- LSTM step 0 ----
  gemm_mfma<<<4 * GY, 256, 0, stream>>>(lstmArgs(0));

  for (int t = 0; t < T_SEQ; ++t) {
    float* stats = statsAll + (size_t)t * 4 * HC;

    // ---- GAT layer 1: GEMM -> edge softmax -> stats ----
    gemm_mfma<<<8 * GY, 256, 0, stream>>>(
        mk(packG1, KP1, wlr1_bf, KP1, nullptr, xlr, 1024, MP, 2 * HC, KP1, 1, 3,
           nullptr, nullptr, nullptr, nullptr, 0, nullptr, nullptr, nullptr, 0));
    gat_edge<<<N_NODES / 4, 256, 0, stream>>>(xlr, att1, bg1, rowstart, csr, gout);
    bn_stats<<<128, 256, 0, stream>>>(gout, stats);

    // ---- GAT layer 2: GEMM with fused BN1+ReLU on A (A = raw gout) ----
    gemm_bn<<<8 * GY, 256, 0, stream>>>(
        mk(gout, HC, wlr2_bf, HC, nullptr, xlr, 1024, MP, 2 * HC, HC, 1, 3,
           nullptr, nullptr, nullptr, nullptr, 0, stats, gamma1, beta1, 1));
    gat_edge<<<N_NODES / 4, 256, 0, stream>>>(xlr, att2, bg2, rowstart, csr, gout);
    bn_stats<<<128, 256, 0, stream>>>(gout, stats + 2 * HC);

    // ---- proj (t, fused BN2+ReLU on A) merged with LSTM GEMM (t+1) ----
    GemmArgs proj = mk(gout, HC, wp_bf, HC, bp, out + t * EMB, T_SEQ * EMB,
                       N_NODES, EMB, HC, 0, 0,
                       nullptr, nullptr, nullptr, nullptr, 0,
                       stats + 2 * HC, gamma2, beta2, 1);
    if (t + 1 < T_SEQ) {
      gemm_dual<<<5 * GY, 256, 0, stream>>>(lstmArgs(t + 1), proj, 4 * GY);
    } else {
      gemm_bn<<<1 * GY, 256, 0, stream>>>(proj);
    }
  }
}